// Round 13
// baseline (6055.563 us; speedup 1.0000x reference)
//
#include <hip/hip_runtime.h>

#define SLEN 64
#define BSZ  64
#define TSL  48
#define VDIM 32000
#define NCOL 32064   // VDIM + SLEN

typedef __attribute__((ext_vector_type(8))) _Float16 f16x8;
typedef __attribute__((ext_vector_type(4))) _Float16 f16x4;
typedef __attribute__((ext_vector_type(4))) float f32x4;

__device__ __forceinline__ float fsig(float x){
    return 1.0f/(1.0f + __expf(-x));
}
__device__ __forceinline__ float ftanh(float x){
    float e = __expf(2.0f*x);
    return 1.0f - 2.0f/(e + 1.0f);
}
__device__ __forceinline__ unsigned short f2h(float x){
    union { _Float16 f; unsigned short u; } c; c.f = (_Float16)x; return c.u;
}
__device__ __forceinline__ float h2f(unsigned short u){
    union { _Float16 f; unsigned short u; } c; c.u = u; return (float)c.f;
}
__device__ __forceinline__ unsigned short f2h_hi(float x, float& rem){
    _Float16 h = (_Float16)x;
    rem = x - (float)h;
    union { _Float16 f; unsigned short u; } c; c.f = h; return c.u;
}
__device__ __forceinline__ float gru_fuse(float gir,float giz,float gin,
                                          float ghr,float ghz,float ghn,float h){
    float r = fsig(gir + ghr);
    float z = fsig(giz + ghz);
    float n = ftanh(gin + r*ghn);
    return (1.0f - z)*n + z*h;
}

// ===========================================================================
// MFMA GEMM (2 param sets): C = A @ B^T + bias, optional tanh.
// c16: write fp16 into (unsigned short*)C instead of fp32.
// ===========================================================================
__global__ __launch_bounds__(256) void mfma_gemm(
    const float* A0, const unsigned short* Bh0, const unsigned short* Bl0,
    const float* bias0, float* C0, int N0, int ldc0, int act0,
    const float* A1, const unsigned short* Bh1, const unsigned short* Bl1,
    const float* bias1, float* C1, int N1, int ldc1, int act1,
    int K, int c16)
{
    const float* A; const unsigned short* Bh; const unsigned short* Bl;
    const float* bias; float* C; int N, ldc, act;
    if (blockIdx.z == 0) { A=A0; Bh=Bh0; Bl=Bl0; bias=bias0; C=C0; N=N0; ldc=ldc0; act=act0; }
    else                 { A=A1; Bh=Bh1; Bl=Bl1; bias=bias1; C=C1; N=N1; ldc=ldc1; act=act1; }

    const int n0 = blockIdx.x * 128;
    if (n0 >= N) return;
    const int m0 = blockIdx.y * 64;

    __shared__ __align__(16) unsigned short As[2][64][72];
    __shared__ __align__(16) unsigned short Bs[2][128][72];

    const int t  = threadIdx.x;
    const int wv = t >> 6, ln = t & 63;
    const bool has_lo = (Bl != nullptr);

    f32x4 acc[4][2];
    #pragma unroll
    for (int i = 0; i < 4; ++i)
        #pragma unroll
        for (int j = 0; j < 2; ++j) acc[i][j] = (f32x4){0.f,0.f,0.f,0.f};

    for (int k0 = 0; k0 < K; k0 += 64) {
        __syncthreads();
        #pragma unroll
        for (int it = 0; it < 4; ++it) {
            int idx = t + it*256;
            int r = idx >> 4, c4 = (idx & 15) * 4;
            float4 v = *reinterpret_cast<const float4*>(A + (size_t)(m0+r)*K + k0 + c4);
            ushort4 h, l; float rm;
            h.x = f2h_hi(v.x, rm); l.x = f2h(rm);
            h.y = f2h_hi(v.y, rm); l.y = f2h(rm);
            h.z = f2h_hi(v.z, rm); l.z = f2h(rm);
            h.w = f2h_hi(v.w, rm); l.w = f2h(rm);
            *reinterpret_cast<ushort4*>(&As[0][r][c4]) = h;
            *reinterpret_cast<ushort4*>(&As[1][r][c4]) = l;
        }
        #pragma unroll
        for (int it = 0; it < 4; ++it) {
            int idx = t + it*256;
            int r = idx >> 3, c8 = (idx & 7) * 8;
            *reinterpret_cast<uint4*>(&Bs[0][r][c8]) =
                *reinterpret_cast<const uint4*>(&Bh[(size_t)(n0+r)*K + k0 + c8]);
        }
        if (has_lo) {
            #pragma unroll
            for (int it = 0; it < 4; ++it) {
                int idx = t + it*256;
                int r = idx >> 3, c8 = (idx & 7) * 8;
                *reinterpret_cast<uint4*>(&Bs[1][r][c8]) =
                    *reinterpret_cast<const uint4*>(&Bl[(size_t)(n0+r)*K + k0 + c8]);
            }
        }
        __syncthreads();
        #pragma unroll
        for (int ks = 0; ks < 2; ++ks) {
            const int ko = ks*32 + (ln >> 4)*8;
            f16x8 ah[4], al[4], bh[2], bl[2];
            #pragma unroll
            for (int m = 0; m < 4; ++m) {
                ah[m] = *reinterpret_cast<const f16x8*>(&As[0][m*16 + (ln&15)][ko]);
                al[m] = *reinterpret_cast<const f16x8*>(&As[1][m*16 + (ln&15)][ko]);
            }
            #pragma unroll
            for (int n = 0; n < 2; ++n) {
                bh[n] = *reinterpret_cast<const f16x8*>(&Bs[0][wv*32 + n*16 + (ln&15)][ko]);
                if (has_lo)
                    bl[n] = *reinterpret_cast<const f16x8*>(&Bs[1][wv*32 + n*16 + (ln&15)][ko]);
            }
            #pragma unroll
            for (int m = 0; m < 4; ++m)
                #pragma unroll
                for (int n = 0; n < 2; ++n) {
                    acc[m][n] = __builtin_amdgcn_mfma_f32_16x16x32_f16(ah[m], bh[n], acc[m][n], 0,0,0);
                    acc[m][n] = __builtin_amdgcn_mfma_f32_16x16x32_f16(al[m], bh[n], acc[m][n], 0,0,0);
                    if (has_lo)
                        acc[m][n] = __builtin_amdgcn_mfma_f32_16x16x32_f16(ah[m], bl[n], acc[m][n], 0,0,0);
                }
        }
    }
    #pragma unroll
    for (int m = 0; m < 4; ++m) {
        #pragma unroll
        for (int n = 0; n < 2; ++n) {
            const int col = n0 + wv*32 + n*16 + (ln & 15);
            const float bz = bias ? bias[col] : 0.0f;
            #pragma unroll
            for (int j = 0; j < 4; ++j) {
                const int row = m0 + m*16 + (ln >> 4)*4 + j;
                float v = acc[m][n][j] + bz;
                if (act) v = ftanh(v);
                if (c16) ((unsigned short*)C)[(size_t)row*ldc + col] = f2h(v);
                else     C[(size_t)row*ldc + col] = v;
            }
        }
    }
}

// ===========================================================================
// Whh pack: P[d][g][k8][col][kk] = Whh[d][g*256+col][k8*8+kk], fp32->fp16.
// ===========================================================================
__global__ __launch_bounds__(256) void packwhh_k(
    const float* __restrict__ Whh, unsigned short* __restrict__ P)
{
    int gidx = blockIdx.x*256 + threadIdx.x;      // 0..49151
    if (gidx >= 2*3*32*256) return;
    int col = gidx & 255;
    int k8  = (gidx >> 8) & 31;
    int g   = (gidx >> 13) % 3;
    int d   = gidx / (3*32*256);
    const float* src = Whh + ((size_t)(d*768 + g*256 + col))*256 + k8*8;
    ushort4 lo4, hi4;
    float4 v0 = *reinterpret_cast<const float4*>(src);
    float4 v1 = *reinterpret_cast<const float4*>(src + 4);
    lo4.x = f2h(v0.x); lo4.y = f2h(v0.y); lo4.z = f2h(v0.z); lo4.w = f2h(v0.w);
    hi4.x = f2h(v1.x); hi4.y = f2h(v1.y); hi4.z = f2h(v1.z); hi4.w = f2h(v1.w);
    reinterpret_cast<ushort4*>(P + (size_t)gidx*8)[0] = lo4;
    reinterpret_cast<ushort4*>(P + (size_t)gidx*8)[1] = hi4;
}

// l2 pack: P[(k8*768+col)*8 + kk] = l2_W[col][k8*8+kk], fp16.
__global__ __launch_bounds__(256) void packl2_k(
    const float* __restrict__ l2W, unsigned short* __restrict__ P)
{
    int i = blockIdx.x*256 + threadIdx.x;   // 0..73727 (96*768)
    if (i >= 96*768) return;
    int col = i % 768, k8 = i / 768;
    const float* src = l2W + (size_t)col*768 + k8*8;
    ushort4 a, b;
    float4 v0 = *reinterpret_cast<const float4*>(src);
    float4 v1 = *reinterpret_cast<const float4*>(src + 4);
    a.x = f2h(v0.x); a.y = f2h(v0.y); a.z = f2h(v0.z); a.w = f2h(v0.w);
    b.x = f2h(v1.x); b.y = f2h(v1.y); b.z = f2h(v1.z); b.w = f2h(v1.w);
    reinterpret_cast<ushort4*>(P + (size_t)i*8)[0] = a;
    reinterpret_cast<ushort4*>(P + (size_t)i*8)[1] = b;
}

// ===========================================================================
// Persistent encoder layer, coalesced packed weights + gi prefetch.
// grid (64, 2), 256 thr (round-9 proven form).
// ===========================================================================
__global__ __launch_bounds__(256) void enc_cp_k(
    const float* __restrict__ giF, const float* __restrict__ giB,
    const unsigned short* __restrict__ Wp,  // packed [d][3][32][256][8]
    const float* __restrict__ bhh,
    float* __restrict__ yout, float* __restrict__ hfin, int permute)
{
    const int b = blockIdx.x, d = blockIdx.y, t = threadIdx.x;
    const float* gi_base = d ? giB : giF;
    const unsigned short* W = Wp + (size_t)d*3*32*256*8;
    const float br  = bhh[d*768 + t];
    const float bz2 = bhh[d*768 + t + 256];
    const float bn  = bhh[d*768 + t + 512];

    __shared__ float hsA[256];
    __shared__ float hsB[256];
    hsA[t] = 0.0f;

    const int s0 = d ? 63 : 0;
    const float* gip0 = gi_base + (size_t)(s0*64 + b)*768;
    float gr = gip0[t], gz = gip0[t+256], gn = gip0[t+512];
    float h_own = 0.0f;
    __syncthreads();

    for (int step = 0; step < 64; ++step) {
        const int s = d ? (63 - step) : step;
        float ngr = 0.f, ngz = 0.f, ngn = 0.f;
        if (step < 63) {
            const int sn = d ? (62 - step) : (step + 1);
            const float* gip = gi_base + (size_t)(sn*64 + b)*768;
            ngr = gip[t]; ngz = gip[t+256]; ngn = gip[t+512];
        }
        const float* hs = (step & 1) ? hsB : hsA;
        float*       hw = (step & 1) ? hsA : hsB;

        float ar = 0.f, az = 0.f, an = 0.f;
        #pragma unroll 8
        for (int k8 = 0; k8 < 32; ++k8) {
            f16x8 wr = *reinterpret_cast<const f16x8*>(W + ((size_t)(0*32 + k8)*256 + t)*8);
            f16x8 wz = *reinterpret_cast<const f16x8*>(W + ((size_t)(1*32 + k8)*256 + t)*8);
            f16x8 wn = *reinterpret_cast<const f16x8*>(W + ((size_t)(2*32 + k8)*256 + t)*8);
            float4 h0 = *reinterpret_cast<const float4*>(&hs[k8*8]);
            float4 h1 = *reinterpret_cast<const float4*>(&hs[k8*8+4]);
            ar += h0.x*(float)wr[0] + h0.y*(float)wr[1] + h0.z*(float)wr[2] + h0.w*(float)wr[3]
                + h1.x*(float)wr[4] + h1.y*(float)wr[5] + h1.z*(float)wr[6] + h1.w*(float)wr[7];
            az += h0.x*(float)wz[0] + h0.y*(float)wz[1] + h0.z*(float)wz[2] + h0.w*(float)wz[3]
                + h1.x*(float)wz[4] + h1.y*(float)wz[5] + h1.z*(float)wz[6] + h1.w*(float)wz[7];
            an += h0.x*(float)wn[0] + h0.y*(float)wn[1] + h0.z*(float)wn[2] + h0.w*(float)wn[3]
                + h1.x*(float)wn[4] + h1.y*(float)wn[5] + h1.z*(float)wn[6] + h1.w*(float)wn[7];
        }
        float r  = fsig(gr + ar + br);
        float z  = fsig(gz + az + bz2);
        float n  = ftanh(gn + r*(an + bn));
        float hn2 = (1.0f - z)*n + z*h_own;
        h_own = hn2;
        hw[t] = hn2;
        const int idx = permute ? (b*64 + s) : (s*64 + b);
        yout[(size_t)idx*512 + d*256 + t] = hn2;
        gr = ngr; gz = ngz; gn = ngn;
        __syncthreads();
    }
    hfin[(size_t)b*512 + d*256 + t] = h_own;
}

// ===========================================================================
// Barrier-light MFMA GRU-GEMM, 512 threads, K split across wave groups.
// E (fp16 [row][2304]) optionally added to gi in gate mode.
// psz!=nullptr: block (z==0,x==0) zeroes psum[512].
// ===========================================================================
__global__ __launch_bounds__(512) void gru_mfma_k(
    const float* A0, const unsigned short* BH0, const unsigned short* BL0,
    const float* bias0, const float* gh0, const float* hold0, float* out0,
    int gate0, int K0, const unsigned short* E0,
    const float* A1, const unsigned short* BH1, const unsigned short* BL1,
    const float* bias1, const float* gh1, const float* hold1, float* out1,
    int gate1, int K1, const unsigned short* E1, float* psz)
{
    const float* A; const unsigned short* BH; const unsigned short* BL;
    const float* bias; const float* gh; const float* hold; float* outp; int gate, K;
    const unsigned short* E;
    if (blockIdx.z == 0) { A=A0; BH=BH0; BL=BL0; bias=bias0; gh=gh0; hold=hold0; outp=out0; gate=gate0; K=K0; E=E0; }
    else                 { A=A1; BH=BH1; BL=BL1; bias=bias1; gh=gh1; hold=hold1; outp=out1; gate=gate1; K=K1; E=E1; }

    const int t = threadIdx.x;
    if (psz && blockIdx.z == 0 && blockIdx.x == 0) psz[t] = 0.f;
    const int w  = t >> 6, ln = t & 63;
    const int rw = w & 3;          // row-wave
    const int kh = w >> 2;         // k-half
    const int colg16 = blockIdx.x * 16;
    const int arow = rw*16 + (ln & 15);
    const int kof  = (ln >> 4) * 8;
    const bool has_lo = (BL != nullptr);

    f32x4 acc[3];
    #pragma unroll
    for (int g = 0; g < 3; ++g) acc[g] = (f32x4){0.f,0.f,0.f,0.f};

    const float* Ar = A + (size_t)arow*K + kof;
    const int brow_n = colg16 + (ln & 15);
    const int Khalf = K >> 1;
    const int kbeg = kh * Khalf;

    #pragma unroll 2
    for (int k0 = kbeg; k0 < kbeg + Khalf; k0 += 32) {
        float4 a0 = *reinterpret_cast<const float4*>(Ar + k0);
        float4 a1 = *reinterpret_cast<const float4*>(Ar + k0 + 4);
        f16x8 ah, al;
        {
            float av0=a0.x, av1=a0.y, av2=a0.z, av3=a0.w;
            float av4=a1.x, av5=a1.y, av6=a1.z, av7=a1.w;
            _Float16 hh;
            hh=(_Float16)av0; ah[0]=hh; al[0]=(_Float16)(av0-(float)hh);
            hh=(_Float16)av1; ah[1]=hh; al[1]=(_Float16)(av1-(float)hh);
            hh=(_Float16)av2; ah[2]=hh; al[2]=(_Float16)(av2-(float)hh);
            hh=(_Float16)av3; ah[3]=hh; al[3]=(_Float16)(av3-(float)hh);
            hh=(_Float16)av4; ah[4]=hh; al[4]=(_Float16)(av4-(float)hh);
            hh=(_Float16)av5; ah[5]=hh; al[5]=(_Float16)(av5-(float)hh);
            hh=(_Float16)av6; ah[6]=hh; al[6]=(_Float16)(av6-(float)hh);
            hh=(_Float16)av7; ah[7]=hh; al[7]=(_Float16)(av7-(float)hh);
        }
        #pragma unroll
        for (int g = 0; g < 3; ++g) {
            const size_t boff = (size_t)(g*768 + brow_n)*K + k0 + kof;
            f16x8 bh = *reinterpret_cast<const f16x8*>(&BH[boff]);
            acc[g] = __builtin_amdgcn_mfma_f32_16x16x32_f16(ah, bh, acc[g], 0,0,0);
            acc[g] = __builtin_amdgcn_mfma_f32_16x16x32_f16(al, bh, acc[g], 0,0,0);
            if (has_lo) {
                f16x8 bl = *reinterpret_cast<const f16x8*>(&BL[boff]);
                acc[g] = __builtin_amdgcn_mfma_f32_16x16x32_f16(ah, bl, acc[g], 0,0,0);
            }
        }
    }

    __shared__ float red[4][64][12];
    if (kh == 1) {
        #pragma unroll
        for (int g = 0; g < 3; ++g)
            #pragma unroll
            for (int j = 0; j < 4; ++j) red[rw][ln][g*4 + j] = acc[g][j];
    }
    __syncthreads();
    if (kh == 1) return;
    #pragma unroll
    for (int g = 0; g < 3; ++g)
        #pragma unroll
        for (int j = 0; j < 4; ++j) acc[g][j] += red[rw][ln][g*4 + j];

    const int colg = colg16 + (ln & 15);
    const int rb   = rw*16 + (ln >> 4)*4;
    if (gate) {
        const float br = bias[colg], bz = bias[768+colg], bn = bias[1536+colg];
        #pragma unroll
        for (int jj = 0; jj < 4; ++jj) {
            const int row = rb + jj;
            float er = 0.f, ez = 0.f, en = 0.f;
            if (E) {
                er = h2f(E[(size_t)row*2304 + colg]);
                ez = h2f(E[(size_t)row*2304 + 768 + colg]);
                en = h2f(E[(size_t)row*2304 + 1536 + colg]);
            }
            float ghr = gh[(size_t)row*2304 + colg];
            float ghz = gh[(size_t)row*2304 + 768 + colg];
            float ghn = gh[(size_t)row*2304 + 1536 + colg];
            float h   = hold[(size_t)row*768 + colg];
            outp[(size_t)row*768 + colg] =
                gru_fuse(acc[0][jj]+br+er, acc[1][jj]+bz+ez, acc[2][jj]+bn+en, ghr, ghz, ghn, h);
        }
    } else {
        #pragma unroll
        for (int g = 0; g < 3; ++g) {
            const float bz = bias[g*768 + colg];
            #pragma unroll
            for (int jj = 0; jj < 4; ++jj)
                outp[(size_t)(rb+jj)*2304 + g*768 + colg] = acc[g][jj] + bz;
        }
    }
}

// ===========================================================================
// MEGA kernel (460 blocks, 512 threads):
//  [0,250)   vocab-z0(t-1):  exp(h1c@embH^T+out_b) -> scrW + psumW
//  [250,314) att(t): inline w2h = h1c@l2^T+l2_b (packed l2P), scores,
//            softmax, Xa -> wgt_in
//  [314,378) smax-finalize(t-2): scrR/cptR/psumR -> outprev
//  [378,396) gh1'(t) = h1c@Whh1^T + bhh1 -> gh1buf
//  [396,460) cpt(t-1) = tanh(scb16 . h1c) -> cptW
// ===========================================================================
__global__ __launch_bounds__(512) void mega_k(
    const float* __restrict__ hv, const unsigned short* __restrict__ embH,
    const float* __restrict__ out_b,
    unsigned short* __restrict__ scrW, float* __restrict__ psumW,
    const unsigned short* __restrict__ w1e16,
    const unsigned short* __restrict__ l2P, const float* __restrict__ l2b,
    const float* __restrict__ Vp, const unsigned short* __restrict__ enc16,
    float* __restrict__ wgt_in,
    const unsigned short* __restrict__ Wh1H, const float* __restrict__ bhh1,
    float* __restrict__ gh1buf,
    const unsigned short* __restrict__ scb16, float* __restrict__ cptW,
    const unsigned short* __restrict__ scrR, const float* __restrict__ cptR,
    const float* __restrict__ psumR,
    const int* __restrict__ y, float* __restrict__ outprev,
    int do_vocab, int do_att, int do_sm, int do_aux, int do_cpt)
{
    __shared__ __align__(16) unsigned short As[2][64][72];
    __shared__ __align__(16) unsigned short Bs[128][72];
    __shared__ float rs[4][64];
    const int bid = blockIdx.x;
    const int t = threadIdx.x, w = t >> 6, ln = t & 63;

    if (bid < 250) {
        if (!do_vocab) return;
        const int n0 = bid * 128;
        const int cw = w & 3, mh = w >> 2;

        f32x4 acc[2][2];
        #pragma unroll
        for (int i = 0; i < 2; ++i)
            #pragma unroll
            for (int j = 0; j < 2; ++j) acc[i][j] = (f32x4){0.f,0.f,0.f,0.f};

        for (int k0 = 0; k0 < 768; k0 += 64) {
            __syncthreads();
            #pragma unroll
            for (int it = 0; it < 2; ++it) {
                int idx = t + it*512;
                int r = idx >> 4, c4 = (idx & 15) * 4;
                float4 v = *reinterpret_cast<const float4*>(hv + (size_t)r*768 + k0 + c4);
                ushort4 h, l; float rm;
                h.x = f2h_hi(v.x, rm); l.x = f2h(rm);
                h.y = f2h_hi(v.y, rm); l.y = f2h(rm);
                h.z = f2h_hi(v.z, rm); l.z = f2h(rm);
                h.w = f2h_hi(v.w, rm); l.w = f2h(rm);
                *reinterpret_cast<ushort4*>(&As[0][r][c4]) = h;
                *reinterpret_cast<ushort4*>(&As[1][r][c4]) = l;
            }
            #pragma unroll
            for (int it = 0; it < 2; ++it) {
                int idx = t + it*512;
                int r = idx >> 3, c8 = (idx & 7) * 8;
                *reinterpret_cast<uint4*>(&Bs[r][c8]) =
                    *reinterpret_cast<const uint4*>(&embH[(size_t)(n0+r)*768 + k0 + c8]);
            }
            __syncthreads();
            #pragma unroll
            for (int ks = 0; ks < 2; ++ks) {
                const int ko = ks*32 + (ln >> 4)*8;
                f16x8 ah[2], al[2], bh[2];
                #pragma unroll
                for (int m = 0; m < 2; ++m) {
                    ah[m] = *reinterpret_cast<const f16x8*>(&As[0][mh*32 + m*16 + (ln&15)][ko]);
                    al[m] = *reinterpret_cast<const f16x8*>(&As[1][mh*32 + m*16 + (ln&15)][ko]);
                }
                #pragma unroll
                for (int n = 0; n < 2; ++n)
                    bh[n] = *reinterpret_cast<const f16x8*>(&Bs[cw*32 + n*16 + (ln&15)][ko]);
                #pragma unroll
                for (int m = 0; m < 2; ++m)
                    #pragma unroll
                    for (int n = 0; n < 2; ++n) {
                        acc[m][n] = __builtin_amdgcn_mfma_f32_16x16x32_f16(ah[m], bh[n], acc[m][n], 0,0,0);
                        acc[m][n] = __builtin_amdgcn_mfma_f32_16x16x32_f16(al[m], bh[n], acc[m][n], 0,0,0);
                    }
            }
        }

        __syncthreads();
        unsigned short (*Cs)[128] = reinterpret_cast<unsigned short(*)[128]>(&As[0][0][0]);
        float sums[2][4];
        #pragma unroll
        for (int m = 0; m < 2; ++m)
            #pragma unroll
            for (int j = 0; j < 4; ++j) sums[m][j] = 0.f;
        #pragma unroll
        for (int m = 0; m < 2; ++m) {
            #pragma unroll
            for (int n = 0; n < 2; ++n) {
                const int cl = cw*32 + n*16 + (ln & 15);
                const float bz = out_b[n0 + cl];
                #pragma unroll
                for (int j = 0; j < 4; ++j) {
                    const int row = mh*32 + m*16 + (ln >> 4)*4 + j;
                    float e = __expf(acc[m][n][j] + bz);
                    Cs[row][cl] = f2h(e);
                    sums[m][j] += e;
                }
            }
        }
        #pragma unroll
        for (int m = 0; m < 2; ++m)
            #pragma unroll
            for (int j = 0; j < 4; ++j) {
                float v = sums[m][j];
                v += __shfl_xor(v, 1); v += __shfl_xor(v, 2);
                v += __shfl_xor(v, 4); v += __shfl_xor(v, 8);
                if ((ln & 15) == 0)
                    rs[cw][mh*32 + m*16 + (ln >> 4)*4 + j] = v;
            }
        __syncthreads();
        #pragma unroll
        for (int it = 0; it < 2; ++it) {
            int jj = t + it*512;
            int row = jj >> 4, c8 = (jj & 15) * 8;
            *reinterpret_cast<uint4*>(&scrW[(size_t)row*VDIM + n0 + c8]) =
                *reinterpret_cast<const uint4*>(&Cs[row][c8]);
        }
        if (t < 64)
            atomicAdd(&psumW[t*8 + (bid & 7)], rs[0][t]+rs[1][t]+rs[2][t]+rs[3][t]);
        return;
    }

    if (bid < 314) {
        if (!do_att) return;
        const int b = bid - 250;
        float* w2s = (float*)&As[0][0][0];
        float* h1s = w2s + 768;
        float* vps = h1s + 768;
        float* aa  = vps + 768;
        for (int i = t; i < 768; i += 512) {
            h1s[i] = hv[(size_t)b*768 + i];
            vps[i] = Vp[i];
        }
        __syncthreads();
        // inline w2h: col t (and col 512+t for t<256)
        {
            float a0 = l2b[t];
            #pragma unroll 8
            for (int k8 = 0; k8 < 96; ++k8) {
                f16x8 wv8 = *reinterpret_cast<const f16x8*>(&l2P[((size_t)k8*768 + t)*8]);
                float4 h0 = *reinterpret_cast<const float4*>(&h1s[k8*8]);
                float4 h1 = *reinterpret_cast<const float4*>(&h1s[k8*8+4]);
                a0 += h0.x*(float)wv8[0] + h0.y*(float)wv8[1] + h0.z*(float)wv8[2] + h0.w*(float)wv8[3]
                    + h1.x*(float)wv8[4] + h1.y*(float)wv8[5] + h1.z*(float)wv8[6] + h1.w*(float)wv8[7];
            }
            w2s[t] = a0;
            if (t < 256) {
                const int c2 = 512 + t;
                float a1 = l2b[c2];
                #pragma unroll 8
                for (int k8 = 0; k8 < 96; ++k8) {
                    f16x8 wv8 = *reinterpret_cast<const f16x8*>(&l2P[((size_t)k8*768 + c2)*8]);
                    float4 h0 = *reinterpret_cast<const float4*>(&h1s[k8*8]);
                    float4 h1 = *reinterpret_cast<const float4*>(&h1s[k8*8+4]);
                    a1 += h0.x*(float)wv8[0] + h0.y*(float)wv8[1] + h0.z*(float)wv8[2] + h0.w*(float)wv8[3]
                        + h1.x*(float)wv8[4] + h1.y*(float)wv8[5] + h1.z*(float)wv8[6] + h1.w*(float)wv8[7];
                }
                w2s[c2] = a1;
            }
        }
        __syncthreads();
        for (int ss = 0; ss < 8; ++ss) {
            const int s = w*8 + ss;
            const unsigned short* wrow = w1e16 + (size_t)(b*64 + s)*768;
            float acc = 0.f;
            #pragma unroll
            for (int q = 0; q < 6; ++q) {
                int e = ln*2 + q*128;
                unsigned u = *reinterpret_cast<const unsigned*>(&wrow[e]);
                acc += ftanh(h2f((unsigned short)(u & 0xffff)) + w2s[e])*vps[e]
                     + ftanh(h2f((unsigned short)(u >> 16))   + w2s[e+1])*vps[e+1];
            }
            for (int off = 32; off; off >>= 1) acc += __shfl_down(acc, off);
            if (ln == 0) aa[s] = acc;
        }
        __syncthreads();
        if (t < 64) {
            float v = aa[t];
            float m = v;
            for (int off = 32; off; off >>= 1) m = fmaxf(m, __shfl_xor(m, off));
            float e = __expf(v - m);
            float ssum = e;
            for (int off = 32; off; off >>= 1) ssum += __shfl_xor(ssum, off);
            aa[t] = e / ssum;
        }
        __syncthreads();
        {
            float a0 = 0.f;
            const unsigned short* ebase = enc16 + (size_t)(b*64)*512 + t;
            #pragma unroll 8
            for (int s = 0; s < 64; ++s)
                a0 += aa[s] * h2f(ebase[(size_t)s*512]);
            wgt_in[(size_t)b*512 + t] = a0;
        }
        return;
    }

    if (bid < 378) {
        if (!do_sm) return;
        const int b = bid - 314;
        float* cps = (float*)&As[0][0][0];
        float* pinv = cps + 64;
        if (t < 64) cps[t] = __expf(cptR[b*64 + t]);
        __syncthreads();
        if (t < 64) {
            float v = cps[t];
            for (int off = 32; off; off >>= 1) v += __shfl_xor(v, off);
            if (t == 0) {
                float tot = v;
                #pragma unroll
                for (int k = 0; k < 8; ++k) tot += psumR[b*8 + k];
                *pinv = 1.0f / tot;
            }
        }
        __syncthreads();
        const float inv = *pinv;
        const unsigned short* srow = scrR + (size_t)b*VDIM;
        float* orow = outprev + (size_t)b*NCOL;
        for (int i = t*8; i < VDIM; i += 4096) {
            uint4 u = *reinterpret_cast<const uint4*>(&srow[i]);
            float4 o0, o1;
            o0.x = h2f((unsigned short)(u.x & 0xffff))*inv; o0.y = h2f((unsigned short)(u.x >> 16))*inv;
            o0.z = h2f((unsigned short)(u.y & 0xffff))*inv; o0.w = h2f((unsigned short)(u.y >> 16))*inv;
            o1.x = h2f((unsigned short)(u.z & 0xffff))*inv; o1.y = h2f((unsigned short)(u.z >> 16))*inv;
            o1.z = h2f((unsigned short)(u.w & 0xffff))*inv; o1.w = h2f((unsigned short)(u.w >> 16))*inv;
            *reinterpret_cast<float4*>(&orow[i])     = o0;
            *reinterpret_cast<float4*>(&orow[i + 4]) = o1;
        }
        if (t >= 448) orow[VDIM + (t - 448)] = 0.0f;
        __syncthreads();
        if (t < 64) atomicAdd(&orow[y[t*64 + b]], cps[t] * inv);
        return;
    }

    if (bid < 396) {
        if (!do_aux) return;
        const int n0 = (bid - 378) * 128;
        const int cw = w & 3, mh = w >> 2;

        f32x4 acc[2][2];
        #pragma unroll
        for (int i = 0; i < 2; ++i)
            #pragma unroll
            for (int j = 0; j < 2; ++j) acc[i][j] = (f32x4){0.f,0.f,0.f,0.f};

        for (int k0 = 0; k0 < 768; k0 += 64) {
            __syncthreads();
            #pragma unroll
            for (int it = 0; it < 2; ++it) {
                int idx = t + it*512;
                int r = idx >> 4, c4 = (idx & 15) * 4;
                float4 v = *reinterpret_cast<const float4*>(hv + (size_t)r*768 + k0 + c4);
                ushort4 h, l; float rm;
                h.x = f2h_hi(v.x, rm); l.x = f2h(rm);
                h.y = f2h_hi(v.y, rm); l.y = f2h(rm);
                h.z = f2h_hi(v.z, rm); l.z = f2h(rm);
                h.w = f2h_hi(v.w, rm); l.w = f2h(rm);
                *reinterpret_cast<ushort4*>(&As[0][r][c4]) = h;
                *reinterpret_cast<ushort4*>(&As[1][r][c4]) = l;
            }
            #pragma unroll
            for (int it = 0; it < 2; ++it) {
                int idx = t + it*512;
                int r = idx >> 3, c8 = (idx & 7) * 8;
                *reinterpret_cast<uint4*>(&Bs[r][c8]) =
                    *reinterpret_cast<const uint4*>(&Wh1H[(size_t)(n0+r)*768 + k0 + c8]);
            }
            __syncthreads();
            #pragma unroll
            for (int ks = 0; ks < 2; ++ks) {
                const int ko = ks*32 + (ln >> 4)*8;
                f16x8 ah[2], al[2], bh[2];
                #pragma unroll
                for (int m = 0; m < 2; ++m) {
                    ah[m] = *reinterpret_cast<const f16x8*>(&As[0][mh*32 + m*16 + (ln&15)][ko]);
                    al[m] = *reinterpret_cast<const f16x8*>(&As[1][mh*32 + m*16 + (ln&15)][ko]);
                }
                #pragma unroll
                for (int n = 0; n < 2; ++n)
                    bh[n] = *reinterpret_cast<const f16x8*>(&Bs[cw*32 + n*16 + (ln&15)][ko]);
                #pragma unroll
                for (int m = 0; m < 2; ++m)
                    #pragma unroll
                    for (int n = 0; n < 2; ++n) {
                        acc[m][n] = __builtin_amdgcn_mfma_f32_16x16x32_f16(ah[m], bh[n], acc[m][n], 0,0,0);
                        acc[m][n] = __builtin_amdgcn_mfma_f32_16x16x32_f16(al[m], bh[n], acc[m][n], 0,0,0);
                    }
            }
        }

        #pragma unroll
        for (int m = 0; m < 2; ++m) {
            #pragma unroll
            for (int n = 0; n < 2; ++n) {
                const int col = n0 + cw*32 + n*16 + (ln & 15);
                const float bz = bhh1[col];
                #pragma unroll
                for (int j = 0; j < 4; ++j) {
                    const int row = mh*32 + m*16 + (ln >> 4)*4 + j;
                    gh1buf[(size_t)row*2304 + col] = acc[m][n][j] + bz;
                }
            }
        }
        return;
    }

    {
        if (!do_cpt) return;
        const int b = bid - 396;
        float* hsh = (float*)&As[0][0][0];
        for (int i = t; i < 768; i += 512) hsh[i] = hv[(size_t)b*768 + i];
        __syncthreads();
        for (int ss = 0; ss < 8; ++ss) {
            const int s = w*8 + ss;
            const unsigned short* sp = scb16 + (size_t)(b*64 + s)*768;
            float acc = 0.f;
            #pragma unroll
            for (int q = 0; q < 6; ++q) {
                int e = ln*2 + q*128;
                unsigned u = *reinterpret_cast<const unsigned*>(&sp[e]);
                acc += h2f((unsigned short)(u & 0xffff))*hsh[e]
                     + h2f((unsigned short)(u >> 16))*hsh[e+1];
            }
            for (int off = 32; off; off >>= 1) acc += __shfl_down(acc, off);
            if (ln == 0) cptW[b*64 + s] = ftanh(acc);
        }
    }
}

// ===========================================================================
// conversions / transposes / small setup kernels
// ===========================================================================
__global__ __launch_bounds__(256) void convhl_k(
    const float* __restrict__ W, unsigned short* __restrict__ hi,
    unsigned short* __restrict__ lo, int n4)
{
    int i = blockIdx.x*256 + threadIdx.x;
    if (i >= n4) return;
    float4 v = reinterpret_cast<const float4*>(W)[i];
    ushort4 h, l; float r;
    h.x = f2h_hi(v.x, r); l.x = f2h(r);
    h.y = f2h_hi(v.y, r); l.y = f2h(r);
    h.z = f2h_hi(v.z, r); l.z = f2h(r);
    h.w = f2h_hi(v.w, r); l.w = f2h(r);
    reinterpret_cast<ushort4*>(hi)[i] = h;
    reinterpret_cast<ushort4*>(lo)[i] = l;
}
__global__ __launch_bounds__(256) void conv16_k(
    const float* __restrict__ W, unsigned short* __restrict__ hi, int n4)
{
    int i = blockIdx.x*256 + threadIdx.x;
    if (i >= n4) return;
    float4 v = reinterpret_cast<const float4*>(W)[i];
    ushort4 h;
    h.x = f2h(v.x); h.y = f2h(v.y); h.z = f2h(v.z); h.w = f2h(v.w);
    reinterpret_cast<ushort4*>(hi)[i] = h;
}
__global__ __launch_bounds__(256) void convw03_k(
    const float* __restrict__ W03f, unsigned short* __restrict__ We,
    unsigned short* __restrict__ Wx)
{
    int i = blockIdx.x*256 + threadIdx.x;
    if (i >= 2304*320) return;
    int r = i / 320, c4 = (i - r*320) * 4;
    float4 v = *reinterpret_cast<const float4*>(W03f + (size_t)r*1280 + c4);
    ushort4 h;
    h.x = f2h(v.x); h.y = f2h(v.y); h.z = f2h(v.z); h.w = f2h(v.w);
    if (c4 < 768)
        *reinterpret_cast<ushort4*>(&We[(size_t)r*768 + c4]) = h;
    else
        *reinterpret_cast<ushort4*>(&Wx[(size_t)r*512 + (c4 - 768)]) = h;
}
__global__ __launch_bounds__(256) void embrows_k(
    const int* __restrict__ y, const float* __restrict__ emb_dec,
    float* __restrict__ Ag)
{
    int i = blockIdx.x*256 + threadIdx.x;
    if (i >= 3072*192) return;
    int row = i / 192, c4 = (i - row*192) * 4;
    int tok = (row < 64) ? 0 : y[row - 64];
    *reinterpret_cast<float4*>(Ag + (size_t)row*768 + c4) =
        *reinterpret_cast<const float4*>(emb_dec + (size_t)tok*768 + c4);
}
__global__ __launch_bounds__(256) void transpose2_k(
    const float* __restrict__ S, float* __restrict__ D, int R, int C)
{
    int i = blockIdx.x*256 + threadIdx.x;
    if (i >= R*C) return;
    int r = i / C, c = i - r*C;
    D[(size_t)c*R + r] = S[i];
}
__global__ __launch_bounds__(256) void b03_k(
    const float* __restrict__ Wih0, const float* __restrict__ bih0,
    const float* __restrict__ l3b, float* __restrict__ b03)
{
    int j = blockIdx.x*256 + threadIdx.x;
    if (j >= 2304) return;
    const float* wr = Wih0 + (size_t)j*768;
    float s = 0.f;
    #pragma unroll 4
    for (int m = 0; m < 768; m += 4) {
        float4 w = *reinterpret_cast<const float4*>(wr + m);
        float4 b = *reinterpret_cast<const float4*>(l3b + m);
        s += w.x*b.x + w.y*b.y + w.z*b.z + w.w*b.w;
    }
    b03[j] = bih0[j] + s;
}

__global__ __launch_bounds__(256) void embed_k(const int* inp, const float* emb, float* x)
{
    int i = blockIdx.x*256 + threadIdx.x;
    if (i >= 4096*128) return;
    int row = i >> 7, c4 = i & 127;
    int tok = inp[row];
    *reinterpret_cast<float4*>(x + (size_t)row*512 + c4*4) =
        *reinterpret_cast<const float4*>(emb + (size_t)tok*512 + c4*4);
}

// ---------------------------------------------------------------------------
// Persistent encoder layer (fp32 VALU fallback), 4 batches/block. grid (16,2).
// ---------------------------------------------------------------------------
__global__ __launch_bounds__(256) void enc_layer4_k(
    const float* giF, const float* giB,
    const unsigned short* Whh16, const float* bhh,
    float* yout, float* hfin, int permute)
{
    const int bg = blockIdx.x, d = blockIdx.y, t = threadIdx.x;
    const float* gi_base = d ? giB : giF;
    const unsigned short* W = Whh16 + (size_t)d*768*256;
    const float br  = bhh[d*768 + t];
    const float bz2 = bhh[d*768 + t + 256];
    const float bn  = bhh[d*768 + t + 512];

    __shared__ float hs[4][256];
    #pragma unroll
    for (int bb = 0; bb < 4; ++bb) hs[bb][t] = 0.0f;
    __syncthreads();

    for (int step = 0; step < 64; ++step) {
        const int s = d ? (63 - step) : step;
        float gr[4], gz[4], gn[4];
        #pragma unroll
        for (int bb = 0; bb < 4; ++bb) {
            const float* gi = gi_base + (size_t)(s*64 + bg*4 + bb)*768;
            gr[bb] = gi[t]; gz[bb] = gi[t+256]; gn[bb] = gi[t+512];
        }
        float ar[4] = {}, az[4] = {}, an[4] = {};
        #pragma unroll 4
        for (int q = 0; q < 32; ++q) {
            f16x8 wr = *reinterpret_cast<const f16x8*>(&W[(size_t)(t      )*256 + q*8]);
            f16x8 wz = *reinterpret_cast<const f16x8*>(&W[(size_t)(t + 256)*256 + q*8]);
            f16x8 wn = *reinterpret_cast<const f16x8*>(&W[(size_t)(t + 512)*256 + q*8]);
            #pragma unroll
            for (int bb = 0; bb < 4; ++bb) {
                float4 h0 = *reinterpret_cast<const float4*>(&hs[bb][q*8]);
                float4 h1 = *reinterpret_cast<const float4*>(&hs[bb][q*8+4]);
                ar[bb] += h0.x*(float)wr[0] + h0.y*(float)wr[1] + h0.z*(float)wr[2] + h0.w*(float)wr[3]
                        + h1.x*(float)wr[4] + h1.y*(float)wr[5] + h1.z*(float)wr[6] + h1.w*(float)wr[7];
                az[bb] += h0.x*(float)wz[0] + h0.y*(float)wz[1] + h0.z*(float)wz[2] + h0.w*(float)wz[3]
                        + h1.x*(float)wz[4] + h1.y*(float)wz[5] + h1.z*(float)wz[6] + h1.w*(float)wz[7];
                an[bb] += h0.x*(float)wn[0] + h0.y*(float)wn[1] + h0.z*(float)wn[2] + h0.w*(float)wn[3]
                        + h1.x*(float)wn[4] + h1.y*(float)wn[5] + h1.z*(float)wn[6] + h1.w*(float)wn[7];
            }
        }
        float hn2[4];
        #pragma unroll
        for (int bb = 0; bb < 4; ++bb) {
            float r = fsig(gr[bb] + ar[bb] + br);
            float z = fsig(gz[bb] + az[bb] + bz2);
            float n = ftanh(gn[bb] + r*(an[bb] + bn));
            hn2[bb] = (1.0f - z)*n + z*hs[bb][t];
        }
        __syncthreads();
        #pragma unroll
        for (int bb = 0; bb < 4; ++bb) {
            hs[bb][t] = hn2[bb];
            const int b = bg*4 + bb;
            const int idx = permute ? (b*64 + s) : (s*64 + b);
            yout[(size_t)idx*512 + d*256 + t] = hn2[bb];
        }
        __syncthreads();
    }
    #pragma unroll
    for (int bb = 0; bb < 4; ++bb)
        hfin[(size_t)(bg*4 + bb)*512 + d*256 + t] = hs[bb][t];
}

// ===========================================================================
// fp32 fallback kernels (only if ws too small for fp16 path)
// ===========================================================================
__global__ __launch_bounds__(256) void gemm64(
    const float* A0, const float* B0, const float* bias0, float* C0, int act0,
    const float* A1, const float* B1, const float* bias1, float* C1, int act1,
    int M, int N, int K, int ldc)
{
    const float* A  = blockIdx.z ? A1 : A0;
    const float* B  = blockIdx.z ? B1 : B0;
    const float* bp = blockIdx.z ? bias1 : bias0;
    float*       C  = blockIdx.z ? C1 : C0;
    const int act   = blockIdx.z ? act1 : act0;

    __shared__ float As[32*68];
    __shared__ float Bs[32*68];

    const int n0 = blockIdx.x * 64;
    const int m0 = blockIdx.y * 64;
    const int t  = threadIdx.x;
    const int lrow = t >> 3;
    const int lc4  = t & 7;
    const int tm = (t >> 4) << 2;
    const int tn = (t & 15) << 2;

    float acc[4][4] = {};

    for (int k0 = 0; k0 < K; k0 += 32) {
        float4 a0 = *reinterpret_cast<const float4*>(A + (size_t)(m0+lrow   )*K + k0 + lc4*4);
        float4 a1 = *reinterpret_cast<const float4*>(A + (size_t)(m0+lrow+32)*K + k0 + lc4*4);
        float4 b0 = *reinterpret_cast<const float4*>(B + (size_t)(n0+lrow   )*K + k0 + lc4*4);
        float4 b1 = *reinterpret_cast<const float4*>(B + (size_t)(n0+lrow+32)*K + k0 + lc4*4);
        __syncthreads();
        const int kb = lc4*4;
        As[(kb+0)*68 + lrow]    = a0.x; As[(kb+1)*68 + lrow]    = a0.y;
        As[(kb+2)*68 + lrow]    = a0.z; As[(kb+3)*68 + lrow]    = a0.w;
        As[(kb+0)*68 + lrow+32] = a1.x; As[(kb+1)*68 + lrow+32] = a1.y;
        As[(kb+2)*68 + lrow+32] = a1.z; As[(kb+3)*68 + lrow+32] = a1.w;
        Bs[(kb+0)*68 + lrow]    = b0.x; Bs[(kb+1)*68 + lrow]    = b0.y;
        Bs[(kb+2)*68 + lrow]    = b0.z; Bs[(kb+3)*68 + lrow]    = b0.w;
        Bs[(kb+0)*68 + lrow+32] = b1.x; Bs[(kb+1)*68 + lrow+32] = b1.y;
        Bs[(kb+2)*68 + lrow+32] = b1.z; Bs[(kb+3)*68 + lrow+32] = b1.w;
        __syncthreads();
        #pragma unroll
        for (int kk = 0; kk < 32; ++kk) {
            float4 av = *reinterpret_cast<const float4*>(As + kk*68 + tm);
            float4 bv = *reinterpret_cast<const float4*>(Bs + kk*68 + tn);
            acc[0][0] += av.x*bv.x; acc[0][1] += av.x*bv.y; acc[0][2] += av.x*bv.z; acc[0][3] += av.x*bv.w;
            acc[1][0] += av.y*bv.x; acc[1][1] += av.y*bv.y; acc[1][2] += av.y*bv.z; acc[1][3] += av.y*bv.w;
            acc[2][0] += av.z*bv.x; acc[2][1] += av.z*bv.y; acc[2][2] += av.z*bv.z; acc[2][3] += av.z*bv.w;
            acc[3][0] += av.w*bv.x; acc[3][1] += av.w*bv.y; acc[3][2] += av.w*bv.z; acc[3][3] += av.w*bv.w;
        }
    }

    #pragma unroll
    for (int i = 0; i < 4; ++i) {
        float r0 = acc[i][0], r1 = acc[i][1], r2 = acc[i][2], r3 = acc[i][3];
        if (bp) { r0 += bp[n0+tn+0]; r1 += bp[n0+tn+1]; r2 += bp[n0+tn+2]; r3 += bp[n0+tn+3]; }
        if (act) { r0 = ftanh(r0); r1 = ftanh(r1); r2 = ftanh(r2); r3 = ftanh(r3); }
        float4 v = make_float4(r0, r1, r2, r3);
        *reinterpret_cast<float4*>(C + (size_t)(m0+tm+i)*ldc + (n0+tn)) = v;
    }
}

__global__ __launch_bounds__(256) void gemm_skinny(
    const float* A0, const float* B0, const float* bias0, float* C0,
    const float* A1, const float* B1, const float* bias1, float* C1,
    int N, int K, int ldc)
{
    const float* A  = blockIdx.z ? A1 : A0;
    const float* B  = blockIdx.z ? B1 : B0;
    const float* bp = blockIdx.z ? bias1 : bias0;
    float*       C  = blockIdx.z ? C1 : C0;

    __shared__ float As[16*64];
    const int n0 = blockIdx.x * 64;
    const int m0 = blockIdx.y * 16;
    const int t  = threadIdx.x;
    const int n  = t & 63;
    const int mb = t >> 6;

    float acc[4] = {};

    for (int k0 = 0; k0 < K; k0 += 64) {
        __syncthreads();
        const int row = t >> 4, c4 = t & 15;
        *reinterpret_cast<float4*>(As + row*64 + c4*4) =
            *reinterpret_cast<const float4*>(A + (size_t)(m0+row)*K + k0 + c4*4);
        __syncthreads();
        const float* Bp = B + (size_t)(n0+n)*K + k0;
        #pragma unroll
        for (int q = 0; q < 16; ++q) {
            float4 bv = *reinterpret_cast<const float4*>(Bp + q*4);
            #pragma unroll
            for (int mm = 0; mm < 4; ++mm) {
                float4 av = *reinterpret_cast<const float4*>(As + (mb + 4*mm)*64 + q*4);
                acc[mm] += av.x*bv.x + av.y*bv.y + av.z*bv.z + av.w*bv.w;
            }
        }
    }
    const float bz = bp ? bp[n0+n] : 0.0f;
    #pragma unroll
    for (int mm = 0; mm < 4; ++mm)
        C[(size_t)(m0 + mb + 4*mm)*ldc + n0 + n] = acc[mm] + bz;
}

__global__ __launch_bounds__(256) void gru_gate_k(
    const float* gi, const float* gh, const float* hold, float* hnew)
{
    int idx = blockIdx.x*256 + threadIdx.x;
    if (idx >= 64*768) return;
    int b = idx / 768, j = idx % 768;
    const float* gib = gi + (size_t)b*2304;
    const float* ghb = gh + (size_t)b*2304;
    hnew[idx] = gru_fuse(gib[j], gib[j+768], gib[j+1536],
                         ghb[j], ghb[j+768], ghb[j+1536], hold[idx]);
}

__global__ __launch_bounds__(256) void att_fused_k(
    const float* __restrict__ w1e, const float* __restrict__ w2h,
    const float* __restrict__ Vp, const float* __restrict__ enc_out,
    const float* __restrict__ emb_dec, const int* __restrict__ y,
    int step, float* __restrict__ wgt_in)
{
    const int b = blockIdx.x, t = threadIdx.x;
    __shared__ float w2s[768];
    __shared__ float vps[768];
    __shared__ float aa[64];
    for (int i = t; i < 768; i += 256) { w2s[i] = w2h[(size_t)b*768 + i]; vps[i] = Vp[i]; }
    __syncthreads();
    const int wv = t >> 6, ln = t & 63;
    for (int ss = 0; ss < 16; ++ss) {
        const int s = wv*16 + ss;
        const float* wrow = w1e + (size_t)(b*64 + s)*768;
        float acc = 0.f;
        #pragma unroll
        for (int q = 0; q < 12; ++q) {
            int e = ln + q*64;
            acc += ftanh(wrow[e] + w2s[e]) * vps[e];
        }
        for (int off = 32; off; off >>= 1) acc += __shfl_down(acc, off);
        if (ln == 0) aa[s] = acc;
    }
    __syncthreads();
    if (t < 64) {
        float v = aa[t];
        float m = v;
        for (int off = 32; off; off >>= 1) m = fmaxf(m, __shfl_xor(m, off));
        float e = __expf(v - m);
        float ssum = e;
        for (int off = 32; off; off >>= 1) ssum += __shfl_xor(ssum, off);
        aa[t] = e / ssum;
    }
    __syncthreads();
    for (int e = t; e < 512; e += 256) {
        float acc = 0.f;
        #pragma unroll 8
        for (int s = 0; s < 64; ++s)
            acc += aa[s] * enc_out[(size_t)(b*64 + s)*512 + e];
        wgt_in[(size_t)b*1280 + 768 + e] = acc;
    }
    const int tok = (step == 0) ? 0 : y[(step-1)*64 + b];
    for (int e = t; e < 768; e += 256)
        wgt_in[(size_t)b*1280 + e] = emb_dec[(size_t)tok*768 + e];
}

__global__ __launch_bounds__(256) void smax2_k(
    const float* __restrict__ scratch, const float* __restrict__ scb,
    const float* __restrict__ h1, const int* __restrict__ y, float* __restrict__ out)
{
    const int b = blockIdx.x, t = threadIdx.x;
    __shared__ float hsh[768];
    __shared__ float cps[64];
    __shared__ float red[4];
    for (int i = t; i < 768; i += 256) hsh[i] = h1[(size_t)b*768 + i];
    __syncthreads();
    const int wv = t >> 6, ln = t & 63;
    for (int ss = 0; ss < 16; ++ss) {
        const int s = wv*16 + ss;
        const float* sp = scb + (size_t)(b*64 + s)*768;
        float acc = 0.f;
        #pragma unroll
        for (int q = 0; q < 12; ++q) { int e = ln + q*64; acc += sp[e]*hsh[e]; }
        for (int off = 32; off; off >>= 1) acc += __shfl_down(acc, off);
        if (ln == 0) cps[s] = ftanh(acc);
    }
    __syncthreads();

    const float* row = scratch + (size_t)b*VDIM;
    float m = -1e30f;
    for (int i = t; i < VDIM; i += 256) m = fmaxf(m, row[i]);
    for (int off = 32; off; off >>= 1) m = fmaxf(m, __shfl_xor(m, off));
    if (ln == 0) red[wv] = m;
    __syncthreads();
    const float bm = fmaxf(fmaxf(red[0], red[1]), fmaxf(red[2], red[3]));
    __syncthreads();

    float s = 0.f;
    for (int i = t; i < VDIM; i += 256) s += __expf(row[i] - bm);
    if (t < 64) s += __expf(cps[t] - bm);
    for (int off = 32; off; off >>= 1) s += __shfl_xor(s, off);
    if (ln == 0) red[wv] = s;
    __syncthreads();
    const float inv = 1.0f / (red[0] + red[1] + red[2] + red[3]);

    float* orow = out + (size_t)b*NCOL;
    for (int i = t; i < VDIM; i += 256) orow[i] = __expf(row[i] - bm) * inv;
    if (t >= 192) orow[VDIM + (t - 192)] = 0.0f;
    __syncthreads();
    if (t < 64) atomicAdd(&orow[y[t*64 + b]], __expf(cps[t] - bm) * inv);
}

// ===========================================================================
extern "C" void kernel_launch(void* const* d_in, const int* in_sizes, int n_in,
                              void* d_out, int out_size, void* d_ws, size_t ws_size,
                              hipStream_t stream)
{
    (void)in_sizes; (void)n_in; (void)out_size;
    const int*   inp       = (const int*)  d_in[0];
    const int*   y         = (const int*)  d_in[1];
    const float* emb_enc   = (const float*)d_in[2];
    const float* enc_Wih   = (const float*)d_in[3];
    const float* enc_Whh   = (const float*)d_in[4];
    const float* enc_bih   = (const float*)d_in[5];
    const float* enc_bhh   = (const float*)d_in[6];
    const float* out_enc_W = (const float*)d_in[7];
    const float* emb_dec   = (const float*)d_in[8];
    const float* dec_Wih   = (const float*)d_in[9];
    const float* dec_Whh   = (const float*)d_in[10];
    const float* dec_bih   = (const float*)d_in[11];
    const float* dec_bhh   = (const float*)d_in[12];
    const float* out_b     = (const float*)d_in[13];
    const float* W1        = (const float*)d_in[14];
    const float* l2_W      = (const float*)d_in[15];
    const float* l2_b      = (const float*)d_in[16];
    const float* l3_W      = (const float*)d_in[17];
    const float* l3_b      = (const float*)d_in[18];
    const float* Vp        = (const float*)d_in[19];
    float* out = (float*)d_out;
    float* ws  = (float*)d_ws;

    size_t off = 0;
    auto alloc = [&](size_t n) { float* p = ws + off; off += (n + 63) & ~(size_t)63; return p; };
    // ---- base region (also serves fp32 fallback) ----
    float* x0     = alloc(4096*512);   // also W03f / Ag temps (span x0+x1 post-encoder)
    float* x1     = alloc(4096*512);
    float* x2     = alloc(4096*512);   // enc_out fp32, rows b*64+s
    float* giF    = alloc(4096*768);   // post-encoder: w1e16 + enc16 (ushort)
    float* giB    = alloc(4096*768);   // post-encoder: scb16 (ushort)
    float* w1e    = alloc(4096*768);
    float* scb    = alloc(4096*768);
    float* W1T    = alloc(768*512);
    float* hfin   = alloc(128*512);
    float* hdecA  = alloc(128*768);
    float* hdecB  = alloc(128*768);
    float* w2h    = alloc(64*768);     // fallback only
    float* wgt_in = alloc(64*1280);
    float* wgt    = alloc(64*768);     // fallback only
    float* gh0buf = alloc(64*2304);
    float* gh1buf = alloc(64*2304);
    float* gi0f   = alloc(64*2304);    // fallback only
    float* gi1f   = alloc(64*2304);    // fallback only
    float* b03    = alloc(2304);
    float* psum   = alloc(1024);       // 2 x (64 rows x 8 slots)
    float* cpt    = alloc(2*4096);     // 2 x copy-score tanh dots
    float* scratch= alloc(64*VDIM);    // fp32 (fallback) / 2 x scr16 bufs / l3T temp
    auto ualloc = [&](size_t nush) { return (unsigned short*)alloc((nush + 1) / 2); };
    unsigned short* encWhhH = ualloc(2*2*768*256);   // linear fp16 (fallback enc)
    unsigned short* encWhhP = ualloc(2*3*32*256*8);  // packed fp16 (mfma-path enc)
    // ---- fp16 region ----
    unsigned short* embH    = ualloc((size_t)VDIM*768);
    unsigned short* encWihH = ualloc(2*2*768*512);
    unsigned short* encWihL = ualloc(2*2*768*512);
    unsigned short* W1TH    = ualloc(768*512);
    unsigned short* W1TL    = ualloc(768*512);
    unsigned short* oeH     = ualloc(768*512);
    unsigned short* oeL     = ualloc(768*512);
    unsigned short* l2H     = ualloc(768*768);
    unsigned short* l2P     = ualloc((size_t)96*768*8);   // packed l2 for inline w2h
    unsigned short* l3TH    = ualloc(1280*768);
    unsigned short* l3TL    = ualloc(1280*768);
    unsigned short* dWihH   = ualloc((size_t)2*2304*768);
    unsigned short* dWhhH   = ualloc((size_t)2*2304*768);
    unsigned short* W03eH   = ualloc((size_t)2304*768);
    unsigned short* W03xH   = ualloc((size_t)2304*512);
    unsigned short* Egi16   = ualloc((size_t)3072*2304);
    const bool use_mfma = ws_size >= off * sizeof(float);

    const size_t L1W = (size_t)2304*768;
    const size_t SCR = (size_t)64*VDIM;   // ushorts per scr16 buffer
    float* l3T  = scratch;             // 1280x768 temp (pre-decoder)
    float* W03f = x0;                  // 2304x1280 temp (post-encoder, spans x0+x1)
    float* Ag   = x0;                  // 3072x768 temp after convw03 (spans x0+x1)
    unsigned short* scr16 = (unsigned short*)scratch;   // 2 buffers of SCR
    unsigned short* w1e16 = (unsigned short*)giF;
    unsigned short* enc16 = (unsigned short*)(giF + 1600*1024);
    unsigned short* scb16 = (unsigned short*)giB;

    // ---- common setup ----
    embed_k<<<2048, 256, 0, stream>>>(inp, emb_enc, x0);
    transpose2_k<<<(512*768 + 255)/256, 256, 0, stream>>>(W1, W1T, 512, 768);
    conv16_k<<<768, 256, 0, stream>>>(enc_Whh, encWhhH, 2*2*768*256/4);

    if (use_mfma) {
        packwhh_k<<<192, 256, 0, stream>>>(enc_Whh, encWhhP);
        convhl_k<<<1536, 256, 0, stream>>>(enc_Wih, encWihH, encWihL, 2*2*768*512/4);
        convhl_k<<<384, 256, 0, stream>>>(W1T, W1TH, W1TL, 768*512/4);
        convhl_k<<<384, 256, 0, stream>>>(out_enc_W, oeH, oeL, 768*512/4);
        conv16_k<<<576, 256, 0, stream>>>(l2_W, l2H, 768*768/4);
        packl2_k<<<288, 256, 0, stream>>>(l2_W, l2P);
        conv16_k<<<3456, 256, 0, stream>>>(dec_Wih, dWihH, (int)(L1W*2/4));
        conv16_k<<<3456, 256, 0, stream>>>(dec_Whh, dWhhH, (int)(L1W*2/4));
        conv16_k<<<24000, 256, 0, stream>>>(emb_dec, embH, (int)((size_t)VDIM*768/4));
        transpose2_k<<<(768*1280 + 255)/256, 256, 0, stream>>>(l3_W, l3T, 768, 1280);
        convhl_k<<<960, 256, 0, stream>>>(l3T, l3TH, l3TL, 1280*768/4);
        b03_k<<<9, 256, 0, stream>>>(dec_Wih, dec_bih, l3_b, b03);

        // ---- encoder (round-9 coalesced form) ----
        for (int l = 0; l < 2; ++l) {
            const float* xin  = l ? x1 : x0;
            float*       xout = l ? x2 : x1;
            const size_t wo = (size_t)l*2*768*512;
            mfma_gemm<<<dim3(6, 64, 2), 256, 0, stream>>>(
                xin, encWihH + wo,           encWihL + wo,           enc_bih + l*2*768,       giF, 768, 768, 0,
                xin, encWihH + wo + 768*512, encWihL + wo + 768*512, enc_bih + l*2*768 + 768, giB, 768, 768, 0,
                512, 0);
            enc_cp_k<<<dim3(64, 2), 256, 0, stream>>>(
                giF, giB, encWhhP, enc_bhh + (size_t)l*2*768,
                xout, hfin + (size_t)l*64*512, l);
            if (l == 0)
                packwhh_k<<<192, 256, 0, stream>>>(enc_Whh + (size_t)2*768*256, encWhhP);
        }

        // W03 = Wih0 @ l3_W (fp32 into x0/x1), then split fp16 -> W03eH/W03xH
        mfma_gemm<<<dim3(10, 36, 1), 256, 0, stream>>>(
            dec_Wih, l3TH, l3TL, nullptr, W03f, 1280, 1280, 0,
            nullptr, nullptr, nullptr, nullptr, nullptr, 0, 0, 0,
            768, 0);
        convw03_k<<<(2304*320 + 255)/256, 256, 0, stream>>>(W03f, W03eH, W03xH);

        // gather dec-input embeddings (all 48 steps) and precompute Egi16
        embrows_k<<<(3072*192 + 255)/256, 256, 0, stream>>>(y, emb_dec, Ag);
        mfma_gemm<<<dim3(18, 48, 1), 256, 0, stream>>>(
            Ag, W03eH, nullptr, nullptr, (float*)Egi16, 2304, 2304, 0,
            nullptr, nullptr, nullptr, nullptr, nullptr, 0, 0, 0,
            768, 1);

        // decoder initial hidden (128,512)@out_enc_W^T
        mfma_gemm<<<dim3(6, 2, 1), 256, 0, stream>>>(
            hfin, oeH, oeL, nullptr, hdecA, 768, 768, 0,
            nullptr, nullptr, nullptr, nullptr, nullptr, 0, 0, 0,
            512, 0);

        // w1e = enc_out@W1 ; scb = tanh(enc_out@out_enc_W^T)
        mfma_gemm<<<dim3(6, 64, 2), 256, 0, stream>>>(
            x2, W1TH, W1TL, nullptr, w1e, 768, 768, 0,
            x2, oeH,  oeL,  nullptr, scb, 768, 768, 1,
            512, 0);

        // fp16 caches: w1e16, scb16, enc16 (giF/giB now free)
        conv16_k<<<3072, 256, 0, stream>>>(w1e, w1e16, 4096*768/4);
        conv16_k<<<3072, 256, 0, stream>>>(scb, scb16, 4096*768/4);
        conv16_k<<<2048, 256, 0, stream>>>(x2, enc16, 4096*512/4);

        // bootstrap: gh0 = h0@Whh0 (gh1 computed inside mega(0))
        gru_mfma_k<<<dim3(48, 1, 1), 512, 0, stream>>>(
            hdecA, dWhhH, nullptr, dec_bhh, nullptr, nullptr, gh0buf, 0, 768, nullptr,
            hdecA, dWhhH, nullptr, dec_bhh, nullptr, nullptr, gh0buf, 0, 768, nullptr,
            nullptr);

        // ---- decoder: 2-deep pipeline, 3 launches/step + 2-launch epilogue ----
        for (int st = 0; st < TSL; ++st) {
            float* h0c = (st & 1) ? hdecB : hdecA;
            float* h0n = (st & 1) ? hdecA : hdecB;
            float* h1c = h0c + 64*768;
            float* h1n = h0n + 64*768;

            // A: vocab(st-1) || att(st, inline w2h) || smax(st-2) || gh1'(st) || cpt(st-1)
            mega_k<<<460, 512, 0, stream>>>(
                h1c, embH, out_b,
                scr16 + ((st+1)&1)*SCR, psum + ((st+1)&1)*512,
                w1e16, l2P, l2_b, Vp, enc16, wgt_in,
                dWhhH + L1W, dec_bhh + 2304, gh1buf,
                scb16, cpt + ((st+1)&1)*4096,
                scr16 + (st&1)*SCR, cpt + (st&1)*4096, psum + (st&1)*512,
                y, out + (size_t)(st >= 2 ? st-2 : 0)*BSZ*NCOL,
                st >= 1, 1, st >= 2, 1, st >= 1);

            // B: gi0 = Xa@W03x^T + Egi16[st] + b03, fused gate0 -> h0n (zeroes psum[st&1])
            gru_mfma_k<<<dim3(48, 1, 1), 512, 0, stream>>>(
                wgt_in, W03xH, nullptr, b03, gh0buf, h0c, h0n, 1, 512, Egi16 + (size_t)st*64*2304,
                wgt_in, W03xH, nullptr, b03, gh0buf, h0c, h0n, 1, 512, Egi16 + (size_t)st*64*2304,
                psum + (st&1)*512);

            // C: gi1+gate1 -> h1n  ||  gh0' = h0n@Whh0 (next step)
            gru_mfma_k<<<dim3(48, 1, 2), 512, 0, stream>>>(
                h0n, dWihH + L1W, nullptr, dec_bih + 2304, gh1buf, h1c, h1n, 1, 768, nullptr,
                h0n, dWhhH,       nullptr, dec_bhh,        nullptr, nullptr, gh0buf, 0, 768, nullptr,
                nullptr);
        }
        // epilogue: mega(48) = vocab(47) || smax(46) || cpt(47);  mega(49) = smax(47)
        {
            int st = TSL;   // 48
            float* h1c = ((st & 1) ? hdecB : hdecA) + 64*768;
            mega_k<<<460, 512, 0, stream>>>(
                h1c, embH, out_b,
                scr16 + ((st+1)&1)*SCR, psum + ((st+1)&1)*512,
                w1e16, l2P, l2_b, Vp, enc16, wgt_in,
                dWhhH + L1W, dec_bhh + 2304, gh1buf,
                scb16, cpt + ((st+1)&1)*4096,
                scr16 + (st&1)*SCR, cpt + (st&1)*4096, psum + (st&1)*512,
                y, out + (size_t)(st-2)*BSZ*NCOL,
                1, 0, 1, 0, 1);
            st = TSL + 1;   // 49
            mega_k<<<460, 512, 0, stream>>>(
                h1c, embH, out_b,
                scr16 + ((st+1)&1)*SCR, psum + ((st+1)&1)*512,
                w1e16, l2P, l2_b, Vp, enc16, wgt_in,
                dWhhH + L1W, dec_bhh + 2304, gh1buf,
                scb16, cpt + ((st+1)&1)*4096,
                scr16 + (st&1)*SCR, cpt + (st&1)*4096, psum + (st&1)*512,
                y, out + (size_t)(st-2)*BSZ*NCOL,
                0, 0, 1, 0, 0);
        }
    } else {
        // ================= fp32 fallback =================
        for (int l = 0; l < 2; ++l) {
            const float* xin  = l ? x1 : x0;
            float*       xout = l ? x2 : x1;
            const float* Wih = enc_Wih + (size_t)l*2*768*512;
            const float* bih = enc_bih + (size_t)l*2*768;
            gemm64<<<dim3(12, 64, 2), 256, 0, stream>>>(
                xin, Wih,           bih,       giF, 0,
                xin, Wih + 768*512, bih + 768, giB, 0,
                4096, 768, 512, 768);
            enc_layer4_k<<<dim3(16, 2), 256, 0, stream>>>(
                giF, giB, encWhhH + (size_t)l*2*768*256, enc_bhh + (size_t)l*2*768,
                xout, hfin + (size_t)l*64*512, l);
        }
        gemm64<<<dim3(12, 2, 1), 256, 0, stream>>>(
            hfin, out_enc_W, nullptr, hdecA, 0,
            hfin, out_enc_W, nullptr, hdecA, 0,
            128, 768, 512, 768);
        gemm64<<<dim3(12, 64, 2), 256, 0, stream>>>(
            x2, W1T,       nullptr, w1e, 0,
            x2, out_enc_W, nullptr, scb, 1,
            4096, 768, 512, 768);
        gemm_skinny<<<dim3(12, 4, 1), 256, 0, stream>>>(
            hdecA + 64*768, l2_W, l2_b, w2h,
            hdecA + 64*768, l2_W, l2_b, w2h,
            768, 768, 768);

        for (int st = 0; st < TSL; ++st) {
            float* h0c = (st & 1) ? hdecB : hdecA;
            float* h0n = (st & 1) ? hdecA : hdecB;
            float* h1c = h0c + 64*768;
            float* h1n = h0n + 64*768;
            float* orow = out + (size_t)st*BSZ*NCOL;

            att_fused_k<<<64, 256, 0, stream>>>(w1e, w2h, Vp, x2, emb_dec, y, st, wgt_in);
            gemm_skinny<<<dim3(12, 4, 1), 256, 0, stream>>>(
                wgt_in, l3_W, l3_b, wgt,
                wgt_in, l3_W, l3_b, wgt,
                768, 1280, 768);
            gemm_skinny<<<dim3(36, 4, 2), 256, 0, stream>>>(
                wgt, dec_Wih, dec_bih, gi0f,
                h0c, dec_Whh, dec_bhh, gh0buf,
                2304, 768, 2304);
            gru_gate_k<<<192, 256, 0, stream>>>(gi0f, gh0buf, h0c, h0n);
            gemm_skinny<<<dim3(36, 4, 2), 256, 0, stream>>>(
                h0n, dec_Wih + L1W, dec_bih + 2304, gi1f,
                h1c, dec_Whh + L1W, dec_bhh + 2304, gh1buf,
                2304, 768, 2304);
            gru_gate_k<<<192, 256, 0, stream>>>(gi1f, gh1buf, h1c, h1n);
            gemm_skinny<<<dim3(12, 4, 1), 256, 0, stream>>>(
                h1n, l2_W, l2_b, w2h,
                h1n, l2_W, l2_b, w2h,
                768, 768, 768);
            gemm64<<<dim3(500, 1, 1), 256, 0, stream>>>(
                h1n, emb_dec, out_b, scratch, 0,
                h1n, emb_dec, out_b, scratch, 0,
                64, VDIM, 768, VDIM);
            smax2_k<<<64, 256, 0, stream>>>(scratch, scb, h1n, y, orow);
        }
    }
}

// Round 14
// 4701.702 us; speedup vs baseline: 1.2880x; 1.2880x over previous
//
#include <hip/hip_runtime.h>

#define SLEN 64
#define BSZ  64
#define TSL  48
#define VDIM 32000
#define NCOL 32064   // VDIM + SLEN

typedef __attribute__((ext_vector_type(8))) _Float16 f16x8;
typedef __attribute__((ext_vector_type(4))) _Float16 f16x4;
typedef __attribute__((ext_vector_type(4))) float f32x4;

__device__ __forceinline__ float fsig(float x){
    return 1.0f/(1.0f + __expf(-x));
}
__device__ __forceinline__ float ftanh(float x){
    float e = __expf(2.0f*x);
    return 1.0f - 2.0f/(e + 1.0f);
}
__device__ __forceinline__ unsigned short f2h(float x){
    union { _Float16 f; unsigned short u; } c; c.f = (_Float16)x; return c.u;
}
__device__ __forceinline__ float h2f(unsigned short u){
    union { _Float16 f; unsigned short u; } c; c.u = u; return (float)c.f;
}
__device__ __forceinline__ unsigned short f2h_hi(float x, float& rem){
    _Float16 h = (_Float16)x;
    rem = x - (float)h;
    union { _Float16 f; unsigned short u; } c; c.f = h; return c.u;
}
__device__ __forceinline__ float gru_fuse(float gir,float giz,float gin,
                                          float ghr,float ghz,float ghn,float h){
    float r = fsig(gir + ghr);
    float z = fsig(giz + ghz);
    float n = ftanh(gin + r*ghn);
    return (1.0f - z)*n + z*h;
}

// ===========================================================================
// MFMA GEMM (2 param sets): C = A @ B^T + bias, optional tanh.
// c16: write fp16 into (unsigned short*)C instead of fp32.
// ===========================================================================
__global__ __launch_bounds__(256) void mfma_gemm(
    const float* A0, const unsigned short* Bh0, const unsigned short* Bl0,
    const float* bias0, float* C0, int N0, int ldc0, int act0,
    const float* A1, const unsigned short* Bh1, const unsigned short* Bl1,
    const float* bias1, float* C1, int N1, int ldc1, int act1,
    int K, int c16)
{
    const float* A; const unsigned short* Bh; const unsigned short* Bl;
    const float* bias; float* C; int N, ldc, act;
    if (blockIdx.z == 0) { A=A0; Bh=Bh0; Bl=Bl0; bias=bias0; C=C0; N=N0; ldc=ldc0; act=act0; }
    else                 { A=A1; Bh=Bh1; Bl=Bl1; bias=bias1; C=C1; N=N1; ldc=ldc1; act=act1; }

    const int n0 = blockIdx.x * 128;
    if (n0 >= N) return;
    const int m0 = blockIdx.y * 64;

    __shared__ __align__(16) unsigned short As[2][64][72];
    __shared__ __align__(16) unsigned short Bs[2][128][72];

    const int t  = threadIdx.x;
    const int wv = t >> 6, ln = t & 63;
    const bool has_lo = (Bl != nullptr);

    f32x4 acc[4][2];
    #pragma unroll
    for (int i = 0; i < 4; ++i)
        #pragma unroll
        for (int j = 0; j < 2; ++j) acc[i][j] = (f32x4){0.f,0.f,0.f,0.f};

    for (int k0 = 0; k0 < K; k0 += 64) {
        __syncthreads();
        #pragma unroll
        for (int it = 0; it < 4; ++it) {
            int idx = t + it*256;
            int r = idx >> 4, c4 = (idx & 15) * 4;
            float4 v = *reinterpret_cast<const float4*>(A + (size_t)(m0+r)*K + k0 + c4);
            ushort4 h, l; float rm;
            h.x = f2h_hi(v.x, rm); l.x = f2h(rm);
            h.y = f2h_hi(v.y, rm); l.y = f2h(rm);
            h.z = f2h_hi(v.z, rm); l.z = f2h(rm);
            h.w = f2h_hi(v.w, rm); l.w = f2h(rm);
            *reinterpret_cast<ushort4*>(&As[0][r][c4]) = h;
            *reinterpret_cast<ushort4*>(&As[1][r][c4]) = l;
        }
        #pragma unroll
        for (int it = 0; it < 4; ++it) {
            int idx = t + it*256;
            int r = idx >> 3, c8 = (idx & 7) * 8;
            *reinterpret_cast<uint4*>(&Bs[0][r][c8]) =
                *reinterpret_cast<const uint4*>(&Bh[(size_t)(n0+r)*K + k0 + c8]);
        }
        if (has_lo) {
            #pragma unroll
            for (int it = 0; it < 4; ++it) {
                int idx = t + it*256;
                int r = idx >> 3, c8 = (idx & 7) * 8;
                *reinterpret_cast<uint4*>(&Bs[1][r][c8]) =
                    *reinterpret_cast<const uint4*>(&Bl[(size_t)(n0+r)*K + k0 + c8]);
            }
        }
        __syncthreads();
        #pragma unroll
        for (int ks = 0; ks < 2; ++ks) {
            const int ko = ks*32 + (ln >> 4)*8;
            f16x8 ah[4], al[4], bh[2], bl[2];
            #pragma unroll
            for (int m = 0; m < 4; ++m) {
                ah[m] = *reinterpret_cast<const f16x8*>(&As[0][m*16 + (ln&15)][ko]);
                al[m] = *reinterpret_cast<const f16x8*>(&As[1][m*16 + (ln&15)][ko]);
            }
            #pragma unroll
            for (int n = 0; n < 2; ++n) {
                bh[n] = *reinterpret_cast<const f16x8*>(&Bs[0][wv*32 + n*16 + (ln&15)][ko]);
                if (has_lo)
                    bl[n] = *reinterpret_cast<const f16x8*>(&Bs[1][wv*32 + n*16 + (ln&15)][ko]);
            }
            #pragma unroll
            for (int m = 0; m < 4; ++m)
                #pragma unroll
                for (int n = 0; n < 2; ++n) {
                    acc[m][n] = __builtin_amdgcn_mfma_f32_16x16x32_f16(ah[m], bh[n], acc[m][n], 0,0,0);
                    acc[m][n] = __builtin_amdgcn_mfma_f32_16x16x32_f16(al[m], bh[n], acc[m][n], 0,0,0);
                    if (has_lo)
                        acc[m][n] = __builtin_amdgcn_mfma_f32_16x16x32_f16(ah[m], bl[n], acc[m][n], 0,0,0);
                }
        }
    }
    #pragma unroll
    for (int m = 0; m < 4; ++m) {
        #pragma unroll
        for (int n = 0; n < 2; ++n) {
            const int col = n0 + wv*32 + n*16 + (ln & 15);
            const float bz = bias ? bias[col] : 0.0f;
            #pragma unroll
            for (int j = 0; j < 4; ++j) {
                const int row = m0 + m*16 + (ln >> 4)*4 + j;
                float v = acc[m][n][j] + bz;
                if (act) v = ftanh(v);
                if (c16) ((unsigned short*)C)[(size_t)row*ldc + col] = f2h(v);
                else     C[(size_t)row*ldc + col] = v;
            }
        }
    }
}

// ===========================================================================
// Whh pack: P[d][g][k8][col][kk] = Whh[d][g*256+col][k8*8+kk], fp32->fp16.
// ===========================================================================
__global__ __launch_bounds__(256) void packwhh_k(
    const float* __restrict__ Whh, unsigned short* __restrict__ P)
{
    int gidx = blockIdx.x*256 + threadIdx.x;      // 0..49151
    if (gidx >= 2*3*32*256) return;
    int col = gidx & 255;
    int k8  = (gidx >> 8) & 31;
    int g   = (gidx >> 13) % 3;
    int d   = gidx / (3*32*256);
    const float* src = Whh + ((size_t)(d*768 + g*256 + col))*256 + k8*8;
    ushort4 lo4, hi4;
    float4 v0 = *reinterpret_cast<const float4*>(src);
    float4 v1 = *reinterpret_cast<const float4*>(src + 4);
    lo4.x = f2h(v0.x); lo4.y = f2h(v0.y); lo4.z = f2h(v0.z); lo4.w = f2h(v0.w);
    hi4.x = f2h(v1.x); hi4.y = f2h(v1.y); hi4.z = f2h(v1.z); hi4.w = f2h(v1.w);
    reinterpret_cast<ushort4*>(P + (size_t)gidx*8)[0] = lo4;
    reinterpret_cast<ushort4*>(P + (size_t)gidx*8)[1] = hi4;
}

// ===========================================================================
// Persistent encoder layer, coalesced packed weights + gi prefetch,
// 512 threads: K split across wave halves (kh = t>>8), LDS reduce.
// grid (64, 2).
// ===========================================================================
__global__ __launch_bounds__(512) void enc_cp5_k(
    const float* __restrict__ giF, const float* __restrict__ giB,
    const unsigned short* __restrict__ Wp,  // packed [d][3][32][256][8]
    const float* __restrict__ bhh,
    float* __restrict__ yout, float* __restrict__ hfin, int permute)
{
    const int b = blockIdx.x, d = blockIdx.y, t = threadIdx.x;
    const int c  = t & 255;        // output column
    const int kh = t >> 8;         // 0 = low k-half (+ gate/finalize), 1 = high
    const float* gi_base = d ? giB : giF;
    const unsigned short* W = Wp + (size_t)d*3*32*256*8;
    const float br  = bhh[d*768 + c];
    const float bz2 = bhh[d*768 + c + 256];
    const float bn  = bhh[d*768 + c + 512];

    __shared__ float hsA[256];
    __shared__ float hsB[256];
    __shared__ float red[3][256];
    if (kh == 0) hsA[c] = 0.0f;

    float gr = 0.f, gz = 0.f, gn = 0.f, h_own = 0.f;
    if (kh == 0) {
        const int s0 = d ? 63 : 0;
        const float* gip0 = gi_base + (size_t)(s0*64 + b)*768;
        gr = gip0[c]; gz = gip0[c+256]; gn = gip0[c+512];
    }
    __syncthreads();

    for (int step = 0; step < 64; ++step) {
        const int s = d ? (63 - step) : step;
        float ngr = 0.f, ngz = 0.f, ngn = 0.f;
        if (kh == 0 && step < 63) {
            const int sn = d ? (62 - step) : (step + 1);
            const float* gip = gi_base + (size_t)(sn*64 + b)*768;
            ngr = gip[c]; ngz = gip[c+256]; ngn = gip[c+512];
        }
        const float* hs = (step & 1) ? hsB : hsA;
        float*       hw = (step & 1) ? hsA : hsB;

        float ar = 0.f, az = 0.f, an = 0.f;
        const int kb = kh * 16;
        #pragma unroll 8
        for (int k8i = 0; k8i < 16; ++k8i) {
            const int k8 = kb + k8i;
            f16x8 wr = *reinterpret_cast<const f16x8*>(W + ((size_t)(0*32 + k8)*256 + c)*8);
            f16x8 wz = *reinterpret_cast<const f16x8*>(W + ((size_t)(1*32 + k8)*256 + c)*8);
            f16x8 wn = *reinterpret_cast<const f16x8*>(W + ((size_t)(2*32 + k8)*256 + c)*8);
            float4 h0 = *reinterpret_cast<const float4*>(&hs[k8*8]);
            float4 h1 = *reinterpret_cast<const float4*>(&hs[k8*8+4]);
            ar += h0.x*(float)wr[0] + h0.y*(float)wr[1] + h0.z*(float)wr[2] + h0.w*(float)wr[3]
                + h1.x*(float)wr[4] + h1.y*(float)wr[5] + h1.z*(float)wr[6] + h1.w*(float)wr[7];
            az += h0.x*(float)wz[0] + h0.y*(float)wz[1] + h0.z*(float)wz[2] + h0.w*(float)wz[3]
                + h1.x*(float)wz[4] + h1.y*(float)wz[5] + h1.z*(float)wz[6] + h1.w*(float)wz[7];
            an += h0.x*(float)wn[0] + h0.y*(float)wn[1] + h0.z*(float)wn[2] + h0.w*(float)wn[3]
                + h1.x*(float)wn[4] + h1.y*(float)wn[5] + h1.z*(float)wn[6] + h1.w*(float)wn[7];
        }
        if (kh == 1) { red[0][c] = ar; red[1][c] = az; red[2][c] = an; }
        __syncthreads();
        if (kh == 0) {
            ar += red[0][c]; az += red[1][c]; an += red[2][c];
            float r  = fsig(gr + ar + br);
            float z  = fsig(gz + az + bz2);
            float n  = ftanh(gn + r*(an + bn));
            float hn2 = (1.0f - z)*n + z*h_own;
            h_own = hn2;
            hw[c] = hn2;
            const int idx = permute ? (b*64 + s) : (s*64 + b);
            yout[(size_t)idx*512 + d*256 + c] = hn2;
            gr = ngr; gz = ngz; gn = ngn;
        }
        __syncthreads();
    }
    if (kh == 0) hfin[(size_t)b*512 + d*256 + c] = h_own;
}

// ===========================================================================
// Barrier-light MFMA GRU-GEMM, 512 threads, K split across wave groups.
// E (fp16 [row][2304]) optionally added to gi in gate mode.
// psz!=nullptr: block (z==0,x==0) zeroes psum[512].
// ===========================================================================
__global__ __launch_bounds__(512) void gru_mfma_k(
    const float* A0, const unsigned short* BH0, const unsigned short* BL0,
    const float* bias0, const float* gh0, const float* hold0, float* out0,
    int gate0, int K0, const unsigned short* E0,
    const float* A1, const unsigned short* BH1, const unsigned short* BL1,
    const float* bias1, const float* gh1, const float* hold1, float* out1,
    int gate1, int K1, const unsigned short* E1, float* psz)
{
    const float* A; const unsigned short* BH; const unsigned short* BL;
    const float* bias; const float* gh; const float* hold; float* outp; int gate, K;
    const unsigned short* E;
    if (blockIdx.z == 0) { A=A0; BH=BH0; BL=BL0; bias=bias0; gh=gh0; hold=hold0; outp=out0; gate=gate0; K=K0; E=E0; }
    else                 { A=A1; BH=BH1; BL=BL1; bias=bias1; gh=gh1; hold=hold1; outp=out1; gate=gate1; K=K1; E=E1; }

    const int t = threadIdx.x;
    if (psz && blockIdx.z == 0 && blockIdx.x == 0) psz[t] = 0.f;
    const int w  = t >> 6, ln = t & 63;
    const int rw = w & 3;          // row-wave
    const int kh = w >> 2;         // k-half
    const int colg16 = blockIdx.x * 16;
    const int arow = rw*16 + (ln & 15);
    const int kof  = (ln >> 4) * 8;
    const bool has_lo = (BL != nullptr);

    f32x4 acc[3];
    #pragma unroll
    for (int g = 0; g < 3; ++g) acc[g] = (f32x4){0.f,0.f,0.f,0.f};

    const float* Ar = A + (size_t)arow*K + kof;
    const int brow_n = colg16 + (ln & 15);
    const int Khalf = K >> 1;
    const int kbeg = kh * Khalf;

    #pragma unroll 2
    for (int k0 = kbeg; k0 < kbeg + Khalf; k0 += 32) {
        float4 a0 = *reinterpret_cast<const float4*>(Ar + k0);
        float4 a1 = *reinterpret_cast<const float4*>(Ar + k0 + 4);
        f16x8 ah, al;
        {
            float av0=a0.x, av1=a0.y, av2=a0.z, av3=a0.w;
            float av4=a1.x, av5=a1.y, av6=a1.z, av7=a1.w;
            _Float16 hh;
            hh=(_Float16)av0; ah[0]=hh; al[0]=(_Float16)(av0-(float)hh);
            hh=(_Float16)av1; ah[1]=hh; al[1]=(_Float16)(av1-(float)hh);
            hh=(_Float16)av2; ah[2]=hh; al[2]=(_Float16)(av2-(float)hh);
            hh=(_Float16)av3; ah[3]=hh; al[3]=(_Float16)(av3-(float)hh);
            hh=(_Float16)av4; ah[4]=hh; al[4]=(_Float16)(av4-(float)hh);
            hh=(_Float16)av5; ah[5]=hh; al[5]=(_Float16)(av5-(float)hh);
            hh=(_Float16)av6; ah[6]=hh; al[6]=(_Float16)(av6-(float)hh);
            hh=(_Float16)av7; ah[7]=hh; al[7]=(_Float16)(av7-(float)hh);
        }
        #pragma unroll
        for (int g = 0; g < 3; ++g) {
            const size_t boff = (size_t)(g*768 + brow_n)*K + k0 + kof;
            f16x8 bh = *reinterpret_cast<const f16x8*>(&BH[boff]);
            acc[g] = __builtin_amdgcn_mfma_f32_16x16x32_f16(ah, bh, acc[g], 0,0,0);
            acc[g] = __builtin_amdgcn_mfma_f32_16x16x32_f16(al, bh, acc[g], 0,0,0);
            if (has_lo) {
                f16x8 bl = *reinterpret_cast<const f16x8*>(&BL[boff]);
                acc[g] = __builtin_amdgcn_mfma_f32_16x16x32_f16(ah, bl, acc[g], 0,0,0);
            }
        }
    }

    __shared__ float red[4][64][12];
    if (kh == 1) {
        #pragma unroll
        for (int g = 0; g < 3; ++g)
            #pragma unroll
            for (int j = 0; j < 4; ++j) red[rw][ln][g*4 + j] = acc[g][j];
    }
    __syncthreads();
    if (kh == 1) return;
    #pragma unroll
    for (int g = 0; g < 3; ++g)
        #pragma unroll
        for (int j = 0; j < 4; ++j) acc[g][j] += red[rw][ln][g*4 + j];

    const int colg = colg16 + (ln & 15);
    const int rb   = rw*16 + (ln >> 4)*4;
    if (gate) {
        const float br = bias[colg], bz = bias[768+colg], bn = bias[1536+colg];
        #pragma unroll
        for (int jj = 0; jj < 4; ++jj) {
            const int row = rb + jj;
            float er = 0.f, ez = 0.f, en = 0.f;
            if (E) {
                er = h2f(E[(size_t)row*2304 + colg]);
                ez = h2f(E[(size_t)row*2304 + 768 + colg]);
                en = h2f(E[(size_t)row*2304 + 1536 + colg]);
            }
            float ghr = gh[(size_t)row*2304 + colg];
            float ghz = gh[(size_t)row*2304 + 768 + colg];
            float ghn = gh[(size_t)row*2304 + 1536 + colg];
            float h   = hold[(size_t)row*768 + colg];
            outp[(size_t)row*768 + colg] =
                gru_fuse(acc[0][jj]+br+er, acc[1][jj]+bz+ez, acc[2][jj]+bn+en, ghr, ghz, ghn, h);
        }
    } else {
        #pragma unroll
        for (int g = 0; g < 3; ++g) {
            const float bz = bias[g*768 + colg];
            #pragma unroll
            for (int jj = 0; jj < 4; ++jj)
                outp[(size_t)(rb+jj)*2304 + g*768 + colg] = acc[g][jj] + bz;
        }
    }
}

// ===========================================================================
// Vocab quad launch, 512 threads. grid (250, 1, 4).
// ===========================================================================
__global__ __launch_bounds__(512) void vocab4_k(
    const float* __restrict__ A,
    const unsigned short* __restrict__ B0, const float* __restrict__ bias0,
    unsigned short* __restrict__ scr16, float* __restrict__ psum,
    const unsigned short* __restrict__ B1, const float* __restrict__ bias1, float* __restrict__ C1,
    const unsigned short* __restrict__ B2, const float* __restrict__ bias2, float* __restrict__ C2,
    const unsigned short* __restrict__ scb16, float* __restrict__ cpt)
{
    const int z = blockIdx.z;
    const int t = threadIdx.x, w = t >> 6, ln = t & 63;

    if (z == 3) {
        const int b = blockIdx.x;
        if (b >= 64) return;
        __shared__ float hsh[768];
        for (int i = t; i < 768; i += 512) hsh[i] = A[(size_t)b*768 + i];
        __syncthreads();
        for (int ss = 0; ss < 8; ++ss) {
            const int s = w*8 + ss;
            const unsigned short* sp = scb16 + (size_t)(b*64 + s)*768;
            float acc = 0.f;
            #pragma unroll
            for (int q = 0; q < 6; ++q) {
                int e = ln*2 + q*128;
                unsigned u = *reinterpret_cast<const unsigned*>(&sp[e]);
                acc += h2f((unsigned short)(u & 0xffff))*hsh[e]
                     + h2f((unsigned short)(u >> 16))*hsh[e+1];
            }
            for (int off = 32; off; off >>= 1) acc += __shfl_down(acc, off);
            if (ln == 0) cpt[b*64 + s] = ftanh(acc);
        }
        return;
    }

    const unsigned short* Bh; const float* bias; int N, ldc;
    if (z == 0)      { Bh=B0; bias=bias0; N=VDIM; ldc=VDIM; }
    else if (z == 1) { Bh=B1; bias=bias1; N=768;  ldc=768; }
    else             { Bh=B2; bias=bias2; N=2304; ldc=2304; }
    const int n0 = blockIdx.x * 128;
    if (n0 >= N) return;

    __shared__ __align__(16) unsigned short As[2][64][72];
    __shared__ __align__(16) unsigned short Bs[128][72];
    __shared__ float rs[4][64];

    const int cw = w & 3;     // col group
    const int mh = w >> 2;    // row half

    f32x4 acc[2][2];
    #pragma unroll
    for (int i = 0; i < 2; ++i)
        #pragma unroll
        for (int j = 0; j < 2; ++j) acc[i][j] = (f32x4){0.f,0.f,0.f,0.f};

    for (int k0 = 0; k0 < 768; k0 += 64) {
        __syncthreads();
        #pragma unroll
        for (int it = 0; it < 2; ++it) {
            int idx = t + it*512;
            int r = idx >> 4, c4 = (idx & 15) * 4;
            float4 v = *reinterpret_cast<const float4*>(A + (size_t)r*768 + k0 + c4);
            ushort4 h, l; float rm;
            h.x = f2h_hi(v.x, rm); l.x = f2h(rm);
            h.y = f2h_hi(v.y, rm); l.y = f2h(rm);
            h.z = f2h_hi(v.z, rm); l.z = f2h(rm);
            h.w = f2h_hi(v.w, rm); l.w = f2h(rm);
            *reinterpret_cast<ushort4*>(&As[0][r][c4]) = h;
            *reinterpret_cast<ushort4*>(&As[1][r][c4]) = l;
        }
        #pragma unroll
        for (int it = 0; it < 2; ++it) {
            int idx = t + it*512;
            int r = idx >> 3, c8 = (idx & 7) * 8;
            *reinterpret_cast<uint4*>(&Bs[r][c8]) =
                *reinterpret_cast<const uint4*>(&Bh[(size_t)(n0+r)*768 + k0 + c8]);
        }
        __syncthreads();
        #pragma unroll
        for (int ks = 0; ks < 2; ++ks) {
            const int ko = ks*32 + (ln >> 4)*8;
            f16x8 ah[2], al[2], bh[2];
            #pragma unroll
            for (int m = 0; m < 2; ++m) {
                ah[m] = *reinterpret_cast<const f16x8*>(&As[0][mh*32 + m*16 + (ln&15)][ko]);
                al[m] = *reinterpret_cast<const f16x8*>(&As[1][mh*32 + m*16 + (ln&15)][ko]);
            }
            #pragma unroll
            for (int n = 0; n < 2; ++n)
                bh[n] = *reinterpret_cast<const f16x8*>(&Bs[cw*32 + n*16 + (ln&15)][ko]);
            #pragma unroll
            for (int m = 0; m < 2; ++m)
                #pragma unroll
                for (int n = 0; n < 2; ++n) {
                    acc[m][n] = __builtin_amdgcn_mfma_f32_16x16x32_f16(ah[m], bh[n], acc[m][n], 0,0,0);
                    acc[m][n] = __builtin_amdgcn_mfma_f32_16x16x32_f16(al[m], bh[n], acc[m][n], 0,0,0);
                }
        }
    }

    if (z == 0) {
        __syncthreads();
        unsigned short (*Cs)[128] = reinterpret_cast<unsigned short(*)[128]>(&As[0][0][0]);
        float sums[2][4];
        #pragma unroll
        for (int m = 0; m < 2; ++m)
            #pragma unroll
            for (int j = 0; j < 4; ++j) sums[m][j] = 0.f;
        #pragma unroll
        for (int m = 0; m < 2; ++m) {
            #pragma unroll
            for (int n = 0; n < 2; ++n) {
                const int cl = cw*32 + n*16 + (ln & 15);
                const float bz = bias[n0 + cl];
                #pragma unroll
                for (int j = 0; j < 4; ++j) {
                    const int row = mh*32 + m*16 + (ln >> 4)*4 + j;
                    float e = __expf(acc[m][n][j] + bz);
                    Cs[row][cl] = f2h(e);
                    sums[m][j] += e;
                }
            }
        }
        #pragma unroll
        for (int m = 0; m < 2; ++m)
            #pragma unroll
            for (int j = 0; j < 4; ++j) {
                float v = sums[m][j];
                v += __shfl_xor(v, 1); v += __shfl_xor(v, 2);
                v += __shfl_xor(v, 4); v += __shfl_xor(v, 8);
                if ((ln & 15) == 0)
                    rs[cw][mh*32 + m*16 + (ln >> 4)*4 + j] = v;
            }
        __syncthreads();
        #pragma unroll
        for (int it = 0; it < 2; ++it) {
            int jj = t + it*512;
            int row = jj >> 4, c8 = (jj & 15) * 8;
            *reinterpret_cast<uint4*>(&scr16[(size_t)row*VDIM + n0 + c8]) =
                *reinterpret_cast<const uint4*>(&Cs[row][c8]);
        }
        if (t < 64)
            atomicAdd(&psum[t*8 + (blockIdx.x & 7)], rs[0][t]+rs[1][t]+rs[2][t]+rs[3][t]);
    } else {
        float* C = (z == 1) ? C1 : C2;
        #pragma unroll
        for (int m = 0; m < 2; ++m) {
            #pragma unroll
            for (int n = 0; n < 2; ++n) {
                const int col = n0 + cw*32 + n*16 + (ln & 15);
                const float bz = bias[col];
                #pragma unroll
                for (int j = 0; j < 4; ++j) {
                    const int row = mh*32 + m*16 + (ln >> 4)*4 + j;
                    C[(size_t)row*ldc + col] = acc[m][n][j] + bz;
                }
            }
        }
    }
}

// ===========================================================================
// Merged attention(step) [y=0] + softmax-finalize(step-1) [y=1].
// grid (64,2), 512 threads. wgt_in = Xa only, stride 512.
// ===========================================================================
__global__ __launch_bounds__(512) void attsm_k(
    const unsigned short* __restrict__ w1e16, const float* __restrict__ w2h,
    const float* __restrict__ Vp, const unsigned short* __restrict__ enc16,
    const int* __restrict__ y,
    int step, int do_att, int do_sm,
    float* __restrict__ wgt_in,
    const unsigned short* __restrict__ scr16, const float* __restrict__ cpt,
    const float* __restrict__ psum, float* __restrict__ outprev)
{
    const int b = blockIdx.x, t = threadIdx.x;
    const int w = t >> 6, ln = t & 63;
    if (blockIdx.y == 0) {
        if (!do_att) return;
        __shared__ float w2s[768];
        __shared__ float vps[768];
        __shared__ float aa[64];
        for (int i = t; i < 768; i += 512) { w2s[i] = w2h[(size_t)b*768 + i]; vps[i] = Vp[i]; }
        __syncthreads();
        for (int ss = 0; ss < 8; ++ss) {
            const int s = w*8 + ss;
            const unsigned short* wrow = w1e16 + (size_t)(b*64 + s)*768;
            float acc = 0.f;
            #pragma unroll
            for (int q = 0; q < 6; ++q) {
                int e = ln*2 + q*128;
                unsigned u = *reinterpret_cast<const unsigned*>(&wrow[e]);
                acc += ftanh(h2f((unsigned short)(u & 0xffff)) + w2s[e])*vps[e]
                     + ftanh(h2f((unsigned short)(u >> 16))   + w2s[e+1])*vps[e+1];
            }
            for (int off = 32; off; off >>= 1) acc += __shfl_down(acc, off);
            if (ln == 0) aa[s] = acc;
        }
        __syncthreads();
        if (t < 64) {
            float v = aa[t];
            float m = v;
            for (int off = 32; off; off >>= 1) m = fmaxf(m, __shfl_xor(m, off));
            float e = __expf(v - m);
            float ssum = e;
            for (int off = 32; off; off >>= 1) ssum += __shfl_xor(ssum, off);
            aa[t] = e / ssum;
        }
        __syncthreads();
        {
            float a0 = 0.f;
            const unsigned short* ebase = enc16 + (size_t)(b*64)*512 + t;
            #pragma unroll 8
            for (int s = 0; s < 64; ++s)
                a0 += aa[s] * h2f(ebase[(size_t)s*512]);
            wgt_in[(size_t)b*512 + t] = a0;
        }
    } else {
        if (!do_sm) return;
        __shared__ float cps[64];
        __shared__ float invS;
        if (t < 64) cps[t] = __expf(cpt[b*64 + t]);
        __syncthreads();
        if (t < 64) {
            float v = cps[t];
            for (int off = 32; off; off >>= 1) v += __shfl_xor(v, off);
            if (t == 0) {
                float tot = v;
                #pragma unroll
                for (int k = 0; k < 8; ++k) tot += psum[b*8 + k];
                invS = 1.0f / tot;
            }
        }
        __syncthreads();
        const float inv = invS;
        const unsigned short* srow = scr16 + (size_t)b*VDIM;
        float* orow = outprev + (size_t)b*NCOL;
        for (int i = t*8; i < VDIM; i += 4096) {
            uint4 u = *reinterpret_cast<const uint4*>(&srow[i]);
            float4 o0, o1;
            o0.x = h2f((unsigned short)(u.x & 0xffff))*inv; o0.y = h2f((unsigned short)(u.x >> 16))*inv;
            o0.z = h2f((unsigned short)(u.y & 0xffff))*inv; o0.w = h2f((unsigned short)(u.y >> 16))*inv;
            o1.x = h2f((unsigned short)(u.z & 0xffff))*inv; o1.y = h2f((unsigned short)(u.z >> 16))*inv;
            o1.z = h2f((unsigned short)(u.w & 0xffff))*inv; o1.w = h2f((unsigned short)(u.w >> 16))*inv;
            *reinterpret_cast<float4*>(&orow[i])     = o0;
            *reinterpret_cast<float4*>(&orow[i + 4]) = o1;
        }
        if (t >= 448) orow[VDIM + (t - 448)] = 0.0f;
        __syncthreads();
        if (t < 64) atomicAdd(&orow[y[t*64 + b]], cps[t] * inv);
    }
}

// ===========================================================================
// conversions / transposes / small setup kernels
// ===========================================================================
__global__ __launch_bounds__(256) void convhl_k(
    const float* __restrict__ W, unsigned short* __restrict__ hi,
    unsigned short* __restrict__ lo, int n4)
{
    int i = blockIdx.x*256 + threadIdx.x;
    if (i >= n4) return;
    float4 v = reinterpret_cast<const float4*>(W)[i];
    ushort4 h, l; float r;
    h.x = f2h_hi(v.x, r); l.x = f2h(r);
    h.y = f2h_hi(v.y, r); l.y = f2h(r);
    h.z = f2h_hi(v.z, r); l.z = f2h(r);
    h.w = f2h_hi(v.w, r); l.w = f2h(r);
    reinterpret_cast<ushort4*>(hi)[i] = h;
    reinterpret_cast<ushort4*>(lo)[i] = l;
}
__global__ __launch_bounds__(256) void conv16_k(
    const float* __restrict__ W, unsigned short* __restrict__ hi, int n4)
{
    int i = blockIdx.x*256 + threadIdx.x;
    if (i >= n4) return;
    float4 v = reinterpret_cast<const float4*>(W)[i];
    ushort4 h;
    h.x = f2h(v.x); h.y = f2h(v.y); h.z = f2h(v.z); h.w = f2h(v.w);
    reinterpret_cast<ushort4*>(hi)[i] = h;
}
__global__ __launch_bounds__(256) void convw03_k(
    const float* __restrict__ W03f, unsigned short* __restrict__ We,
    unsigned short* __restrict__ Wx)
{
    int i = blockIdx.x*256 + threadIdx.x;
    if (i >= 2304*320) return;
    int r = i / 320, c4 = (i - r*320) * 4;
    float4 v = *reinterpret_cast<const float4*>(W03f + (size_t)r*1280 + c4);
    ushort4 h;
    h.x = f2h(v.x); h.y = f2h(v.y); h.z = f2h(v.z); h.w = f2h(v.w);
    if (c4 < 768)
        *reinterpret_cast<ushort4*>(&We[(size_t)r*768 + c4]) = h;
    else
        *reinterpret_cast<ushort4*>(&Wx[(size_t)r*512 + (c4 - 768)]) = h;
}
__global__ __launch_bounds__(256) void embrows_k(
    const int* __restrict__ y, const float* __restrict__ emb_dec,
    float* __restrict__ Ag)
{
    int i = blockIdx.x*256 + threadIdx.x;
    if (i >= 3072*192) return;
    int row = i / 192, c4 = (i - row*192) * 4;
    int tok = (row < 64) ? 0 : y[row - 64];
    *reinterpret_cast<float4*>(Ag + (size_t)row*768 + c4) =
        *reinterpret_cast<const float4*>(emb_dec + (size_t)tok*768 + c4);
}
__global__ __launch_bounds__(256) void transpose2_k(
    const float* __restrict__ S, float* __restrict__ D, int R, int C)
{
    int i = blockIdx.x*256 + threadIdx.x;
    if (i >= R*C) return;
    int r = i / C, c = i - r*C;
    D[(size_t)c*R + r] = S[i];
}
__global__ __launch_bounds__(256) void b03_k(
    const float* __restrict__ Wih0, const float* __restrict__ bih0,
    const float* __restrict__ l3b, float* __restrict__ b03)
{
    int j = blockIdx.x*256 + threadIdx.x;
    if (j >= 2304) return;
    const float* wr = Wih0 + (size_t)j*768;
    float s = 0.f;
    #pragma unroll 4
    for (int m = 0; m < 768; m += 4) {
        float4 w = *reinterpret_cast<const float4*>(wr + m);
        float4 b = *reinterpret_cast<const float4*>(l3b + m);
        s += w.x*b.x + w.y*b.y + w.z*b.z + w.w*b.w;
    }
    b03[j] = bih0[j] + s;
}

__global__ __launch_bounds__(256) void embed_k(const int* inp, const float* emb, float* x)
{
    int i = blockIdx.x*256 + threadIdx.x;
    if (i >= 4096*128) return;
    int row = i >> 7, c4 = i & 127;
    int tok = inp[row];
    *reinterpret_cast<float4*>(x + (size_t)row*512 + c4*4) =
        *reinterpret_cast<const float4*>(emb + (size_t)tok*512 + c4*4);
}

// ---------------------------------------------------------------------------
// Persistent encoder layer (fp32 VALU fallback), 4 batches/block. grid (16,2).
// ---------------------------------------------------------------------------
__global__ __launch_bounds__(256) void enc_layer4_k(
    const float* giF, const float* giB,
    const unsigned short* Whh16, const float* bhh,
    float* yout, float* hfin, int permute)
{
    const int bg = blockIdx.x, d = blockIdx.y, t = threadIdx.x;
    const float* gi_base = d ? giB : giF;
    const unsigned short* W = Whh16 + (size_t)d*768*256;
    const float br  = bhh[d*768 + t];
    const float bz2 = bhh[d*768 + t + 256];
    const float bn  = bhh[d*768 + t + 512];

    __shared__ float hs[4][256];
    #pragma unroll
    for (int bb = 0; bb < 4; ++bb) hs[bb][t] = 0.0f;
    __syncthreads();

    for (int step = 0; step < 64; ++step) {
        const int s = d ? (63 - step) : step;
        float gr[4], gz[4], gn[4];
        #pragma unroll
        for (int bb = 0; bb < 4; ++bb) {
            const float* gi = gi_base + (size_t)(s*64 + bg*4 + bb)*768;
            gr[bb] = gi[t]; gz[bb] = gi[t+256]; gn[bb] = gi[t+512];
        }
        float ar[4] = {}, az[4] = {}, an[4] = {};
        #pragma unroll 4
        for (int q = 0; q < 32; ++q) {
            f16x8 wr = *reinterpret_cast<const f16x8*>(&W[(size_t)(t      )*256 + q*8]);
            f16x8 wz = *reinterpret_cast<const f16x8*>(&W[(size_t)(t + 256)*256 + q*8]);
            f16x8 wn = *reinterpret_cast<const f16x8*>(&W[(size_t)(t + 512)*256 + q*8]);
            #pragma unroll
            for (int bb = 0; bb < 4; ++bb) {
                float4 h0 = *reinterpret_cast<const float4*>(&hs[bb][q*8]);
                float4 h1 = *reinterpret_cast<const float4*>(&hs[bb][q*8+4]);
                ar[bb] += h0.x*(float)wr[0] + h0.y*(float)wr[1] + h0.z*(float)wr[2] + h0.w*(float)wr[3]
                        + h1.x*(float)wr[4] + h1.y*(float)wr[5] + h1.z*(float)wr[6] + h1.w*(float)wr[7];
                az[bb] += h0.x*(float)wz[0] + h0.y*(float)wz[1] + h0.z*(float)wz[2] + h0.w*(float)wz[3]
                        + h1.x*(float)wz[4] + h1.y*(float)wz[5] + h1.z*(float)wz[6] + h1.w*(float)wz[7];
                an[bb] += h0.x*(float)wn[0] + h0.y*(float)wn[1] + h0.z*(float)wn[2] + h0.w*(float)wn[3]
                        + h1.x*(float)wn[4] + h1.y*(float)wn[5] + h1.z*(float)wn[6] + h1.w*(float)wn[7];
            }
        }
        float hn2[4];
        #pragma unroll
        for (int bb = 0; bb < 4; ++bb) {
            float r = fsig(gr[bb] + ar[bb] + br);
            float z = fsig(gz[bb] + az[bb] + bz2);
            float n = ftanh(gn[bb] + r*(an[bb] + bn));
            hn2[bb] = (1.0f - z)*n + z*hs[bb][t];
        }
        __syncthreads();
        #pragma unroll
        for (int bb = 0; bb < 4; ++bb) {
            hs[bb][t] = hn2[bb];
            const int b = bg*4 + bb;
            const int idx = permute ? (b*64 + s) : (s*64 + b);
            yout[(size_t)idx*512 + d*256 + t] = hn2[bb];
        }
        __syncthreads();
    }
    #pragma unroll
    for (int bb = 0; bb < 4; ++bb)
        hfin[(size_t)(bg*4 + bb)*512 + d*256 + t] = hs[bb][t];
}

// ===========================================================================
// fp32 fallback kernels (only if ws too small for fp16 path)
// ===========================================================================
__global__ __launch_bounds__(256) void gemm64(
    const float* A0, const float* B0, const float* bias0, float* C0, int act0,
    const float* A1, const float* B1, const float* bias1, float* C1, int act1,
    int M, int N, int K, int ldc)
{
    const float* A  = blockIdx.z ? A1 : A0;
    const float* B  = blockIdx.z ? B1 : B0;
    const float* bp = blockIdx.z ? bias1 : bias0;
    float*       C  = blockIdx.z ? C1 : C0;
    const int act   = blockIdx.z ? act1 : act0;

    __shared__ float As[32*68];
    __shared__ float Bs[32*68];

    const int n0 = blockIdx.x * 64;
    const int m0 = blockIdx.y * 64;
    const int t  = threadIdx.x;
    const int lrow = t >> 3;
    const int lc4  = t & 7;
    const int tm = (t >> 4) << 2;
    const int tn = (t & 15) << 2;

    float acc[4][4] = {};

    for (int k0 = 0; k0 < K; k0 += 32) {
        float4 a0 = *reinterpret_cast<const float4*>(A + (size_t)(m0+lrow   )*K + k0 + lc4*4);
        float4 a1 = *reinterpret_cast<const float4*>(A + (size_t)(m0+lrow+32)*K + k0 + lc4*4);
        float4 b0 = *reinterpret_cast<const float4*>(B + (size_t)(n0+lrow   )*K + k0 + lc4*4);
        float4 b1 = *reinterpret_cast<const float4*>(B + (size_t)(n0+lrow+32)*K + k0 + lc4*4);
        __syncthreads();
        const int kb = lc4*4;
        As[(kb+0)*68 + lrow]    = a0.x; As[(kb+1)*68 + lrow]    = a0.y;
        As[(kb+2)*68 + lrow]    = a0.z; As[(kb+3)*68 + lrow]    = a0.w;
        As[(kb+0)*68 + lrow+32] = a1.x; As[(kb+1)*68 + lrow+32] = a1.y;
        As[(kb+2)*68 + lrow+32] = a1.z; As[(kb+3)*68 + lrow+32] = a1.w;
        Bs[(kb+0)*68 + lrow]    = b0.x; Bs[(kb+1)*68 + lrow]    = b0.y;
        Bs[(kb+2)*68 + lrow]    = b0.z; Bs[(kb+3)*68 + lrow]    = b0.w;
        Bs[(kb+0)*68 + lrow+32] = b1.x; Bs[(kb+1)*68 + lrow+32] = b1.y;
        Bs[(kb+2)*68 + lrow+32] = b1.z; Bs[(kb+3)*68 + lrow+32] = b1.w;
        __syncthreads();
        #pragma unroll
        for (int kk = 0; kk < 32; ++kk) {
            float4 av = *reinterpret_cast<const float4*>(As + kk*68 + tm);
            float4 bv = *reinterpret_cast<const float4*>(Bs + kk*68 + tn);
            acc[0][0] += av.x*bv.x; acc[0][1] += av.x*bv.y; acc[0][2] += av.x*bv.z; acc[0][3] += av.x*bv.w;
            acc[1][0] += av.y*bv.x; acc[1][1] += av.y*bv.y; acc[1][2] += av.y*bv.z; acc[1][3] += av.y*bv.w;
            acc[2][0] += av.z*bv.x; acc[2][1] += av.z*bv.y; acc[2][2] += av.z*bv.z; acc[2][3] += av.z*bv.w;
            acc[3][0] += av.w*bv.x; acc[3][1] += av.w*bv.y; acc[3][2] += av.w*bv.z; acc[3][3] += av.w*bv.w;
        }
    }

    #pragma unroll
    for (int i = 0; i < 4; ++i) {
        float r0 = acc[i][0], r1 = acc[i][1], r2 = acc[i][2], r3 = acc[i][3];
        if (bp) { r0 += bp[n0+tn+0]; r1 += bp[n0+tn+1]; r2 += bp[n0+tn+2]; r3 += bp[n0+tn+3]; }
        if (act) { r0 = ftanh(r0); r1 = ftanh(r1); r2 = ftanh(r2); r3 = ftanh(r3); }
        float4 v = make_float4(r0, r1, r2, r3);
        *reinterpret_cast<float4*>(C + (size_t)(m0+tm+i)*ldc + (n0+tn)) = v;
    }
}

__global__ __launch_bounds__(256) void gemm_skinny(
    const float* A0, const float* B0, const float* bias0, float* C0,
    const float* A1, const float* B1, const float* bias1, float* C1,
    int N, int K, int ldc)
{
    const float* A  = blockIdx.z ? A1 : A0;
    const float* B  = blockIdx.z ? B1 : B0;
    const float* bp = blockIdx.z ? bias1 : bias0;
    float*       C  = blockIdx.z ? C1 : C0;

    __shared__ float As[16*64];
    const int n0 = blockIdx.x * 64;
    const int m0 = blockIdx.y * 16;
    const int t  = threadIdx.x;
    const int n  = t & 63;
    const int mb = t >> 6;

    float acc[4] = {};

    for (int k0 = 0; k0 < K; k0 += 64) {
        __syncthreads();
        const int row = t >> 4, c4 = t & 15;
        *reinterpret_cast<float4*>(As + row*64 + c4*4) =
            *reinterpret_cast<const float4*>(A + (size_t)(m0+row)*K + k0 + c4*4);
        __syncthreads();
        const float* Bp = B + (size_t)(n0+n)*K + k0;
        #pragma unroll
        for (int q = 0; q < 16; ++q) {
            float4 bv = *reinterpret_cast<const float4*>(Bp + q*4);
            #pragma unroll
            for (int mm = 0; mm < 4; ++mm) {
                float4 av = *reinterpret_cast<const float4*>(As + (mb + 4*mm)*64 + q*4);
                acc[mm] += av.x*bv.x + av.y*bv.y + av.z*bv.z + av.w*bv.w;
            }
        }
    }
    const float bz = bp ? bp[n0+n] : 0.0f;
    #pragma unroll
    for (int mm = 0; mm < 4; ++mm)
        C[(size_t)(m0 + mb + 4*mm)*ldc + n0 + n] = acc[mm] + bz;
}

__global__ __launch_bounds__(256) void gru_gate_k(
    const float* gi, const float* gh, const float* hold, float* hnew)
{
    int idx = blockIdx.x*256 + threadIdx.x;
    if (idx >= 64*768) return;
    int b = idx / 768, j = idx % 768;
    const float* gib = gi + (size_t)b*2304;
    const float* ghb = gh + (size_t)b*2304;
    hnew[idx] = gru_fuse(gib[j], gib[j+768], gib[j+1536],
                         ghb[j], ghb[j+768], ghb[j+1536], hold[idx]);
}

__global__ __launch_bounds__(256) void att_fused_k(
    const float* __restrict__ w1e, const float* __restrict__ w2h,
    const float* __restrict__ Vp, const float* __restrict__ enc_out,
    const float* __restrict__ emb_dec, const int* __restrict__ y,
    int step, float* __restrict__ wgt_in)
{
    const int b = blockIdx.x, t = threadIdx.x;
    __shared__ float w2s[768];
    __shared__ float vps[768];
    __shared__ float aa[64];
    for (int i = t; i < 768; i += 256) { w2s[i] = w2h[(size_t)b*768 + i]; vps[i] = Vp[i]; }
    __syncthreads();
    const int wv = t >> 6, ln = t & 63;
    for (int ss = 0; ss < 16; ++ss) {
        const int s = wv*16 + ss;
        const float* wrow = w1e + (size_t)(b*64 + s)*768;
        float acc = 0.f;
        #pragma unroll
        for (int q = 0; q < 12; ++q) {
            int e = ln + q*64;
            acc += ftanh(wrow[e] + w2s[e]) * vps[e];
        }
        for (int off = 32; off; off >>= 1) acc += __shfl_down(acc, off);
        if (ln == 0) aa[s] = acc;
    }
    __syncthreads();
    if (t < 64) {
        float v = aa[t];
        float m = v;
        for (int off = 32; off; off >>= 1) m = fmaxf(m, __shfl_xor(m, off));
        float e = __expf(v - m);
        float ssum = e;
        for (int off = 32; off; off >>= 1) ssum += __shfl_xor(ssum, off);
        aa[t] = e / ssum;
    }
    __syncthreads();
    for (int e = t; e < 512; e += 256) {
        float acc = 0.f;
        #pragma unroll 8
        for (int s = 0; s < 64; ++s)
            acc += aa[s] * enc_out[(size_t)(b*64 + s)*512 + e];
        wgt_in[(size_t)b*1280 + 768 + e] = acc;
    }
    const int tok = (step == 0) ? 0 : y[(step-1)*64 + b];
    for (int e = t; e < 768; e += 256)
        wgt_in[(size_t)b*1280 + e] = emb_dec[(size_t)tok*768 + e];
}

__global__ __launch_bounds__(256) void smax2_k(
    const float* __restrict__ scratch, const float* __restrict__ scb,
    const float* __restrict__ h1, const int* __restrict__ y, float* __restrict__ out)
{
    const int b = blockIdx.x, t = threadIdx.x;
    __shared__ float hsh[768];
    __shared__ float cps[64];
    __shared__ float red[4];
    for (int i = t; i < 768; i += 256) hsh[i] = h1[(size_t)b*768 + i];
    __syncthreads();
    const int wv = t >> 6, ln = t & 63;
    for (int ss = 0; ss < 16; ++ss) {
        const int s = wv*16 + ss;
        const float* sp = scb + (size_t)(b*64 + s)*768;
        float acc = 0.f;
        #pragma unroll
        for (int q = 0; q < 12; ++q) { int e = ln + q*64; acc += sp[e]*hsh[e]; }
        for (int off = 32; off; off >>= 1) acc += __shfl_down(acc, off);
        if (ln == 0) cps[s] = ftanh(acc);
    }
    __syncthreads();

    const float* row = scratch + (size_t)b*VDIM;
    float m = -1e30f;
    for (int i = t; i < VDIM; i += 256) m = fmaxf(m, row[i]);
    for (int off = 32; off; off >>= 1) m = fmaxf(m, __shfl_xor(m, off));
    if (ln == 0) red[wv] = m;
    __syncthreads();
    const float bm = fmaxf(fmaxf(red[0], red[1]), fmaxf(red[2], red[3]));
    __syncthreads();

    float s = 0.f;
    for (int i = t; i < VDIM; i += 256) s += __expf(row[i] - bm);
    if (t < 64) s += __expf(cps[t] - bm);
    for (int off = 32; off; off >>= 1) s += __shfl_xor(s, off);
    if (ln == 0) red[wv] = s;
    __syncthreads();
    const float inv = 1.0f / (red[0] + red[1] + red[2] + red[3]);

    float* orow = out + (size_t)b*NCOL;
    for (int i = t; i < VDIM; i += 256) orow[i] = __expf(row[i] - bm) * inv;
    if (t >= 192) orow[VDIM + (t - 192)] = 0.0f;
    __syncthreads();
    if (t < 64) atomicAdd(&orow[y[t*64 + b]], __expf(cps[t] - bm) * inv);
}

// ===========================================================================
extern "C" void kernel_launch(void* const* d_in, const int* in_sizes, int n_in,
                              void* d_out, int out_size, void* d_ws, size_t ws_size,
                              hipStream_t stream)
{
    (void)in_sizes; (void)n_in; (void)out_size;
    const int*   inp       = (const int*)  d_in[0];
    const int*   y         = (const int*)  d_in[1];
    const float* emb_enc   = (const float*)d_in[2];
    const float* enc_Wih   = (const float*)d_in[3];
    const float* enc_Whh   = (const float*)d_in[4];
    const float* enc_bih   = (const float*)d_in[5];
    const float* enc_bhh   = (const float*)d_in[6];
    const float* out_enc_W = (const float*)d_in[7];
    const float* emb_dec   = (const float*)d_in[8];
    const float* dec_Wih   = (const float*)d_in[9];
    const float* dec_Whh   = (const float*)d_in[10];
    const float* dec_bih   = (const float*)d_in[11];
    const float* dec_bhh   = (const float*)d_in[12];
    const float* out_b     = (const float*)d_in[13];
    const float* W1        = (const float*)d_in[14];
    const float* l2_W      = (const float*)d_in[15];
    const float* l2_b      = (const float*)d_in[16];
    const float* l3_W      = (const float*)d_in[17];
    const float* l3_b      = (const float*)d_in[18];
    const float* Vp        = (const float*)d_in[19];
    float* out = (float*)d_out;
    float* ws  = (float*)d_ws;

    size_t off = 0;
    auto alloc = [&](size_t n) { float* p = ws + off; off += (n + 63) & ~(size_t)63; return p; };
    // ---- base region (also serves fp32 fallback) ----
    float* x0     = alloc(4096*512);   // also W03f / Ag temps (span x0+x1 post-encoder)
    float* x1     = alloc(4096*512);
    float* x2     = alloc(4096*512);   // enc_out fp32, rows b*64+s
    float* giF    = alloc(4096*768);   // post-encoder: w1e16 + enc16 (ushort)
    float* giB    = alloc(4096*768);   // post-encoder: scb16 (ushort)
    float* w1e    = alloc(4096*768);
    float* scb    = alloc(4096*768);
    float* W1T    = alloc(768*512);
    float* hfin   = alloc(128*512);
    float* hdecA  = alloc(128*768);
    float* hdecB  = alloc(128*768);
    float* w2h    = alloc(64*768);
    float* wgt_in = alloc(64*1280);
    float* wgt    = alloc(64*768);     // fallback only
    float* gh0buf = alloc(64*2304);
    float* gh1buf = alloc(64*2304);
    float* gi0f   = alloc(64*2304);    // fallback only
    float* gi1f   = alloc(64*2304);    // fallback only
    float* b03    = alloc(2304);
    float* psum   = alloc(1024);       // 2 x (64 rows x 8 slots)
    float* cpt    = alloc(2*4096);     // 2 x copy-score tanh dots
    float* scratch= alloc(64*VDIM);    // fp32 (fallback) / 2 x scr16 bufs / l3T temp
    auto ualloc = [&](size_t nush) { return (unsigned short*)alloc((nush + 1) / 2); };
    unsigned short* encWhhH = ualloc(2*2*768*256);   // linear fp16 (fallback enc)
    unsigned short* encWhhP = ualloc(2*3*32*256*8);  // packed fp16 (mfma-path enc)
    // ---- fp16 region ----
    unsigned short* embH    = ualloc((size_t)VDIM*768);
    unsigned short* encWihH = ualloc(2*2*768*512);
    unsigned short* encWihL = ualloc(2*2*768*512);
    unsigned short* W1TH    = ualloc(768*512);
    unsigned short* W1TL    = ualloc(768*512);
    unsigned short* oeH     = ualloc(768*512);
    unsigned short* oeL     = ualloc(768*512);
    unsigned short* l2H     = ualloc(768*768);
    unsigned short* l3TH    = ualloc(1280*768);
    unsigned short* l3TL    = ualloc(1280*768);
    unsigned short* dWihH   = ualloc((size_t)2*2304*768);
    unsigned short* dWhhH   = ualloc((size_t)2*2304*768);
    unsigned short* W03eH   = ualloc((size_t)2304*768);
    unsigned short* W03xH   = ualloc((size_t)2304*512);
    unsigned short* Egi16   = ualloc((size_t)3072*2304);
    const bool use_mfma = ws_size >= off * sizeof(float);

    const size_t L1W = (size_t)2304*768;
    const size_t SCR = (size_t)64*VDIM;   // ushorts per scr16 buffer
    float* l3T  = scratch;             // 1280x768 temp (pre-decoder)
    float* W03f = x0;                  // 2304x1280 temp (post-encoder, spans x0+x1)
    float* Ag   = x0;                  // 3072x768 temp after convw03 (spans x0+x1)
    unsigned short* scr16 = (unsigned short*)scratch;   // 2 buffers of SCR
    unsigned short* w1e16 = (unsigned short*)giF;
    unsigned short* enc16 = (unsigned short*)(giF + 1600*1024);
    unsigned short* scb16 = (unsigned short*)giB;

    // ---- common setup ----
    embed_k<<<2048, 256, 0, stream>>>(inp, emb_enc, x0);
    transpose2_k<<<(512*768 + 255)/256, 256, 0, stream>>>(W1, W1T, 512, 768);
    conv16_k<<<768, 256, 0, stream>>>(enc_Whh, encWhhH, 2*2*768*256/4);

    if (use_mfma) {
        packwhh_k<<<192, 256, 0, stream>>>(enc_Whh, encWhhP);
        convhl_k<<<1536, 256, 0, stream>>>(enc_Wih, encWihH, encWihL, 2*2*768*512/4);
        convhl_k<<<384, 256, 0, stream>>>(W1T, W1TH, W1TL, 768*512/4);
        convhl_k<<<384, 256, 0, stream>>>(out_enc_W, oeH, oeL, 768*512/4);
        conv16_k<<<576, 256, 0, stream>>>(l2_W, l2H, 768*768/4);
        conv16_k<<<3456, 256, 0, stream>>>(dec_Wih, dWihH, (int)(L1W*2/4));
        conv16_k<<<3456, 256, 0, stream>>>(dec_Whh, dWhhH, (int)(L1W*2/4));
        conv16_k<<<24000, 256, 0, stream>>>(emb_dec, embH, (int)((size_t)VDIM*768/4));
        transpose2_k<<<(768*1280 + 255)/256, 256, 0, stream>>>(l3_W, l3T, 768, 1280);
        convhl_k<<<960, 256, 0, stream>>>(l3T, l3TH, l3TL, 1280*768/4);
        b03_k<<<9, 256, 0, stream>>>(dec_Wih, dec_bih, l3_b, b03);

        // ---- encoder (512-thread K-split recurrence) ----
        for (int l = 0; l < 2; ++l) {
            const float* xin  = l ? x1 : x0;
            float*       xout = l ? x2 : x1;
            const size_t wo = (size_t)l*2*768*512;
            mfma_gemm<<<dim3(6, 64, 2), 256, 0, stream>>>(
                xin, encWihH + wo,           encWihL + wo,           enc_bih + l*2*768,       giF, 768, 768, 0,
                xin, encWihH + wo + 768*512, encWihL + wo + 768*512, enc_bih + l*2*768 + 768, giB, 768, 768, 0,
                512, 0);
            enc_cp5_k<<<dim3(64, 2), 512, 0, stream>>>(
                giF, giB, encWhhP, enc_bhh + (size_t)l*2*768,
                xout, hfin + (size_t)l*64*512, l);
            if (l == 0)
                packwhh_k<<<192, 256, 0, stream>>>(enc_Whh + (size_t)2*768*256, encWhhP);
        }

        // W03 = Wih0 @ l3_W (fp32 into x0/x1), then split fp16 -> W03eH/W03xH
        mfma_gemm<<<dim3(10, 36, 1), 256, 0, stream>>>(
            dec_Wih, l3TH, l3TL, nullptr, W03f, 1280, 1280, 0,
            nullptr, nullptr, nullptr, nullptr, nullptr, 0, 0, 0,
            768, 0);
        convw03_k<<<(2304*320 + 255)/256, 256, 0, stream>>>(W03f, W03eH, W03xH);

        // gather dec-input embeddings (all 48 steps) and precompute Egi16
        embrows_k<<<(3072*192 + 255)/256, 256, 0, stream>>>(y, emb_dec, Ag);
        mfma_gemm<<<dim3(18, 48, 1), 256, 0, stream>>>(
            Ag, W03eH, nullptr, nullptr, (float*)Egi16, 2304, 2304, 0,
            nullptr, nullptr, nullptr, nullptr, nullptr, 0, 0, 0,
            768, 1);

        // decoder initial hidden (128,512)@out_enc_W^T
        mfma_gemm<<<dim3(6, 2, 1), 256, 0, stream>>>(
            hfin, oeH, oeL, nullptr, hdecA, 768, 768, 0,
            nullptr, nullptr, nullptr, nullptr, nullptr, 0, 0, 0,
            512, 0);

        // w1e = enc_out@W1 ; scb = tanh(enc_out@out_enc_W^T)
        mfma_gemm<<<dim3(6, 64, 2), 256, 0, stream>>>(
            x2, W1TH, W1TL, nullptr, w1e, 768, 768, 0,
            x2, oeH,  oeL,  nullptr, scb, 768, 768, 1,
            512, 0);

        // fp16 caches: w1e16, scb16, enc16 (giF/giB now free)
        conv16_k<<<3072, 256, 0, stream>>>(w1e, w1e16, 4096*768/4);
        conv16_k<<<3072, 256, 0, stream>>>(scb, scb16, 4096*768/4);
        conv16_k<<<2048, 256, 0, stream>>>(x2, enc16, 4096*512/4);

        // bootstrap: w2h = h1@l2 ; gh0 = h0@Whh0 ; gh1 = h1@Whh1
        mfma_gemm<<<dim3(6, 1, 1), 256, 0, stream>>>(
            hdecA + 64*768, l2H, nullptr, l2_b, w2h, 768, 768, 0,
            nullptr, nullptr, nullptr, nullptr, nullptr, 0, 0, 0,
            768, 0);
        gru_mfma_k<<<dim3(48, 1, 2), 512, 0, stream>>>(
            hdecA,          dWhhH,       nullptr, dec_bhh,        nullptr, nullptr, gh0buf, 0, 768, nullptr,
            hdecA + 64*768, dWhhH + L1W, nullptr, dec_bhh + 2304, nullptr, nullptr, gh1buf, 0, 768, nullptr,
            nullptr);

        // ---- decoder: 2-deep pipeline, 4 launches/step + 2-launch epilogue ----
        for (int st = 0; st < TSL; ++st) {
            float* h0c = (st & 1) ? hdecB : hdecA;
            float* h0n = (st & 1) ? hdecA : hdecB;
            float* h1c = h0c + 64*768;
            float* h1n = h0n + 64*768;
            float* oprev = out + (size_t)(st > 0 ? st - 1 : 0)*BSZ*NCOL;

            attsm_k<<<dim3(64, 2), 512, 0, stream>>>(
                w1e16, w2h, Vp, enc16, y, st, 1, (st > 0) ? 1 : 0,
                wgt_in, scr16, cpt, psum, oprev);

            // gi0 = Xa@W03x^T + Egi16[st] + b03, fused gate0 -> h0n (zeroes psum)
            gru_mfma_k<<<dim3(48, 1, 1), 512, 0, stream>>>(
                wgt_in, W03xH, nullptr, b03, gh0buf, h0c, h0n, 1, 512, Egi16 + (size_t)st*64*2304,
                wgt_in, W03xH, nullptr, b03, gh0buf, h0c, h0n, 1, 512, Egi16 + (size_t)st*64*2304,
                psum);

            // gi1+gate1 -> h1n  ||  gh0' = h0n@Whh0 (next step)
            gru_mfma_k<<<dim3(48, 1, 2), 512, 0, stream>>>(
                h0n, dWihH + L1W, nullptr, dec_bih + 2304, gh1buf, h1c, h1n, 1, 768, nullptr,
                h0n, dWhhH,       nullptr, dec_bhh,        nullptr, nullptr, gh0buf, 0, 768, nullptr,
                nullptr);

            // vocab exp->scr16+psum || w2h' || gh1' || copy-scores cpt
            vocab4_k<<<dim3(250, 1, 4), 512, 0, stream>>>(
                h1n,
                embH, out_b, scr16, psum,
                l2H, l2_b, w2h,
                dWhhH + L1W, dec_bhh + 2304, gh1buf,
                scb16, cpt);
        }
        // final softmax for step 47
        attsm_k<<<dim3(64, 2), 512, 0, stream>>>(
            w1e16, w2h, Vp, enc16, y, TSL, 0, 1,
            wgt_in, scr16, cpt, psum, out + (size_t)(TSL-1)*BSZ*NCOL);
    } else {
        // ================= fp32 fallback =================
        for (int l = 0; l < 2; ++l) {
            const float* xin  = l ? x1 : x0;
            float*       xout = l ? x2 : x1;
            const float* Wih = enc_Wih + (size_t)l*2*768*512;
            const float* bih = enc_bih + (size_t)l*2*768;
            gemm64<<<dim3(12, 64, 2), 256, 0, stream>>>(
                xin, Wih,           bih,       giF, 0,
                xin, Wih + 768*512, bih + 768, giB, 0,
                4096, 768, 512, 768);
            enc_layer4_k<<<dim3(16, 2), 256, 0, stream>>>(
                giF, giB, encWhhH + (size_t)l*2*768*256, enc_bhh + (size_t)l*2*768,
                xout, hfin + (size_t)l*64*512, l);
        }
        gemm64<<<dim3(12, 2, 1), 256, 0, stream>>>(
            hfin, out_enc_W, nullptr, hdecA, 0,
            hfin, out_enc_W, nullptr, hdecA, 0,
            128, 768, 512, 768);
        gemm64<<<dim3(12, 64, 2), 256, 0, stream>>>(
            x2, W1T,       nullptr, w1e, 0,
            x2, out_enc_W, nullptr, scb, 1,
            4096, 768, 512, 768);
        gemm_skinny<<<dim3(12, 4, 1), 256, 0, stream>>>(
            hdecA + 64*768, l2_W, l2_b, w2h,
            hdecA + 64*768, l2_W, l2_b, w2h,
            768, 768, 768);

        for (int st = 0; st < TSL; ++st) {
            float* h0c = (st & 1) ? hdecB : hdecA;
            float* h0n = (st & 1) ? hdecA : hdecB;
            float* h1c = h0c + 64*768;
            float* h1n = h0n + 64*768;
            float* orow = out + (size_t)st*BSZ*NCOL;

            att_fused_k<<<64, 256, 0, stream>>>(w1e, w2h, Vp, x2, emb_dec, y, st, wgt_in);
            gemm_skinny<<<dim3(12, 4, 1), 256, 0, stream>>>(
                wgt_in, l3_W, l3_b, wgt,
                wgt_in, l3_W, l3_b, wgt,
                768, 1280, 768);
            gemm_skinny<<<dim3(36, 4, 2), 256, 0, stream>>>(
                wgt, dec_Wih, dec_bih, gi0f,
                h0c, dec_Whh, dec_bhh, gh0buf,
                2304, 768, 2304);
            gru_gate_k<<<192, 256, 0, stream>>>(gi0f, gh0buf, h0c, h0n);
            gemm_skinny<<<dim3(36, 4, 2), 256, 0, stream>>>(
                h0n, dec_Wih + L1W, dec_bih + 2304, gi1f,
                h1c, dec_Whh + L1W, dec_bhh + 2304, gh1buf,
                2304, 768, 2304);
            gru_gate_k<<<192, 256, 0, stream>>>(gi1f, gh1buf, h1c, h1n);
            gemm_skinny<<<dim3(12, 4, 1), 256, 0, stream>>>(
                h1n, l2_W, l2_b, w2h,
                h1n, l2_W, l2_b, w2h,
                768, 768, 768);
            gemm64<<<dim3(500, 1, 1), 256, 0, stream>>>(
                h1n, emb_dec, out_b, scratch, 0,
                h1n, emb_dec, out_b, scratch, 0,
                64, VDIM, 768, VDIM);
            smax2_k<<<64, 256, 0, stream>>>(scratch, scb, h1n, y, orow);
        }
    }
}